// Round 1
// baseline (630.572 us; speedup 1.0000x reference)
//
#include <hip/hip_runtime.h>
#include <math.h>

#define J 25
#define CIN 3
#define HID 64
#define LAT 32
#define FPB 2            // frames per block
#define HPAD 68          // padded row stride for h (breaks 64-stride bank aliasing)

// ws layout (floats): A1s[625] | App[625] | A4s[625] | bpp[64]
#define WS_A1  0
#define WS_APP 625
#define WS_A4  1250
#define WS_BPP 1875

// ---------------------------------------------------------------------------
// Precompute: row-softmax of A1..A4; App = A3s @ A2s; bpp = W3^T b2 + b3.
// Single block, 256 threads. Runs every launch (ws is re-poisoned).
// ---------------------------------------------------------------------------
__global__ void gcn_precompute(const float* __restrict__ A1,
                               const float* __restrict__ A2,
                               const float* __restrict__ A3,
                               const float* __restrict__ A4,
                               const float* __restrict__ W3,
                               const float* __restrict__ b2,
                               const float* __restrict__ b3,
                               float* __restrict__ ws)
{
    __shared__ float A2s[J * J];
    __shared__ float A3s[J * J];
    const int t = threadIdx.x;

    if (t < 4 * J) {                       // 100 softmax rows
        const int m = t / J, i = t % J;
        const float* Asrc = (m == 0) ? A1 : (m == 1) ? A2 : (m == 2) ? A3 : A4;
        float row[J];
        float mx = -1e30f;
        #pragma unroll
        for (int j = 0; j < J; j++) { row[j] = Asrc[i * J + j]; mx = fmaxf(mx, row[j]); }
        float s = 0.f;
        #pragma unroll
        for (int j = 0; j < J; j++) { row[j] = expf(row[j] - mx); s += row[j]; }
        const float inv = 1.f / s;
        if (m == 0) {
            #pragma unroll
            for (int j = 0; j < J; j++) ws[WS_A1 + i * J + j] = row[j] * inv;
        } else if (m == 1) {
            #pragma unroll
            for (int j = 0; j < J; j++) A2s[i * J + j] = row[j] * inv;
        } else if (m == 2) {
            #pragma unroll
            for (int j = 0; j < J; j++) A3s[i * J + j] = row[j] * inv;
        } else {
            #pragma unroll
            for (int j = 0; j < J; j++) ws[WS_A4 + i * J + j] = row[j] * inv;
        }
    }
    __syncthreads();

    // App = A3s @ A2s
    for (int idx = t; idx < J * J; idx += blockDim.x) {
        const int i = idx / J, jj = idx % J;
        float s = 0.f;
        #pragma unroll
        for (int k = 0; k < J; k++) s += A3s[i * J + k] * A2s[k * J + jj];
        ws[WS_APP + idx] = s;
    }

    // bpp[d] = b3[d] + sum_l W3[l][d] * b2[l]
    if (t < HID) {
        float s = b3[t];
        #pragma unroll
        for (int l = 0; l < LAT; l++) s += W3[l * HID + t] * b2[l];
        ws[WS_BPP + t] = s;
    }
}

// ---------------------------------------------------------------------------
// Fused main kernel: all 4 graph-convs for FPB frames per block, LDS-resident.
//   y  = A1s @ x            (mix-first: Cin=3)
//   h  = relu(y @ W1 + b1)
//   u  = h @ W2              (proj-first: 64 -> 32 bottleneck)
//   v  = App @ u             (App = A3s@A2s; b2 folds into bpp)
//   hd = relu(v @ W3 + bpp)
//   p  = hd @ W4             (proj-first: 64 -> 3)
//   out= A4s @ p + b4
// ---------------------------------------------------------------------------
__global__ __launch_bounds__(256, 2) void gcn_fused(
    const float* __restrict__ x,
    const float* __restrict__ W1, const float* __restrict__ b1,
    const float* __restrict__ W2,
    const float* __restrict__ W4, const float* __restrict__ b4,
    const float* __restrict__ ws,
    float* __restrict__ out,
    const float* __restrict__ W3full)
{
    __shared__ float A1s[J * J], App[J * J], A4s[J * J];
    __shared__ float W1s[CIN * HID], b1s[HID], bpps[HID], W4s[HID * CIN], b4s[CIN];
    __shared__ float xs[FPB * J * CIN];     // 150; reused as p in L4
    __shared__ float ys[FPB * J * CIN];     // 150
    __shared__ float hs[FPB * J * HPAD];    // 3400 (reused for h_dec)
    __shared__ float us[FPB * J * LAT];     // 1600
    __shared__ float vs[FPB * J * LAT];     // 1600

    const int t = threadIdx.x;
    const int fbase = blockIdx.x * FPB;

    // ---- constants -> LDS
    for (int i = t; i < J * J; i += 256) {
        A1s[i] = ws[WS_A1 + i];
        App[i] = ws[WS_APP + i];
        A4s[i] = ws[WS_A4 + i];
    }
    for (int i = t; i < CIN * HID; i += 256) W1s[i] = W1[i];
    for (int i = t; i < HID * CIN; i += 256) W4s[i] = W4[i];
    if (t < HID) { b1s[t] = b1[t]; bpps[t] = ws[WS_BPP + t]; }
    if (t < CIN) b4s[t] = b4[t];

    // ---- per-thread weight columns (register-resident, shared across frames)
    float W2col[HID];                       // column (t&31) of W2 [64x32]
    {
        const int l = t & 31;
        #pragma unroll
        for (int c = 0; c < HID; c++) W2col[c] = W2[c * LAT + l];
    }
    float W3col[LAT];                       // column (t&63) of W3 [32x64]
    {
        const int d = t & 63;
        #pragma unroll
        for (int l = 0; l < LAT; l++) W3col[l] = W3full[l * HID + d];
    }

    // ---- load x tile (150 contiguous floats)
    if (t < FPB * J * CIN) xs[t] = x[fbase * (J * CIN) + t];
    __syncthreads();

    // ---- L1 mix: ys[f][i][c] = sum_j A1s[i][j] * xs[f][j][c]
    if (t < FPB * J * CIN) {
        const int f = t / (J * CIN), r = t % (J * CIN), i = r / CIN, c = r % CIN;
        float s = 0.f;
        #pragma unroll
        for (int j = 0; j < J; j++) s += A1s[i * J + j] * xs[f * (J * CIN) + j * CIN + c];
        ys[t] = s;
    }
    __syncthreads();

    // ---- L1 proj: hs[R][d] = relu(b1[d] + sum_c ys[R][c] * W1[c][d])
    {
        const int d = t & 63, g = t >> 6;   // 4 row-groups
        for (int R = g; R < FPB * J; R += 4) {
            float s = b1s[d];
            #pragma unroll
            for (int c = 0; c < CIN; c++) s += ys[R * CIN + c] * W1s[c * HID + d];
            hs[R * HPAD + d] = fmaxf(s, 0.f);
        }
    }
    __syncthreads();

    // ---- L2: us[R][l] = sum_c hs[R][c] * W2col[c]
    {
        const int l = t & 31, g = t >> 5;   // 8 row-groups
        for (int R = g; R < FPB * J; R += 8) {
            const float4* h4 = reinterpret_cast<const float4*>(&hs[R * HPAD]);
            float s = 0.f;
            #pragma unroll
            for (int c4 = 0; c4 < HID / 4; c4++) {
                const float4 hv = h4[c4];
                s += hv.x * W2col[4 * c4 + 0] + hv.y * W2col[4 * c4 + 1]
                   + hv.z * W2col[4 * c4 + 2] + hv.w * W2col[4 * c4 + 3];
            }
            us[R * LAT + l] = s;
        }
    }
    __syncthreads();

    // ---- mid mix: vs[f][i][l] = sum_j App[i][j] * us[f][j][l]
    {
        const int l = t & 31, g = t >> 5;
        for (int R = g; R < FPB * J; R += 8) {
            const int f = R / J, i = R % J;
            float s = 0.f;
            #pragma unroll
            for (int j = 0; j < J; j++) s += App[i * J + j] * us[(f * J + j) * LAT + l];
            vs[R * LAT + l] = s;
        }
    }
    __syncthreads();

    // ---- L3: hs[R][d] = relu(bpp[d] + sum_l vs[R][l] * W3col[l])   (overwrite hs)
    {
        const int d = t & 63, g = t >> 6;
        for (int R = g; R < FPB * J; R += 4) {
            const float4* v4 = reinterpret_cast<const float4*>(&vs[R * LAT]);
            float s = bpps[d];
            #pragma unroll
            for (int l4 = 0; l4 < LAT / 4; l4++) {
                const float4 vv = v4[l4];
                s += vv.x * W3col[4 * l4 + 0] + vv.y * W3col[4 * l4 + 1]
                   + vv.z * W3col[4 * l4 + 2] + vv.w * W3col[4 * l4 + 3];
            }
            hs[R * HPAD + d] = fmaxf(s, 0.f);
        }
    }
    __syncthreads();

    // ---- L4 proj: p[R][c] = sum_d hs[R][d] * W4[d][c]   (p stored in xs)
    if (t < FPB * J * CIN) {
        const int r = t % (J * CIN), R = (t / (J * CIN)) * J + r / CIN, c = r % CIN;
        const float4* h4 = reinterpret_cast<const float4*>(&hs[R * HPAD]);
        float s = 0.f;
        #pragma unroll
        for (int d4 = 0; d4 < HID / 4; d4++) {
            const float4 hv = h4[d4];
            s += hv.x * W4s[(4 * d4 + 0) * CIN + c] + hv.y * W4s[(4 * d4 + 1) * CIN + c]
               + hv.z * W4s[(4 * d4 + 2) * CIN + c] + hv.w * W4s[(4 * d4 + 3) * CIN + c];
        }
        xs[t] = s;
    }
    __syncthreads();

    // ---- L4 mix + store: out[f][i][c] = b4[c] + sum_j A4s[i][j] * p[f][j][c]
    if (t < FPB * J * CIN) {
        const int f = t / (J * CIN), r = t % (J * CIN), i = r / CIN, c = r % CIN;
        float s = b4s[c];
        #pragma unroll
        for (int j = 0; j < J; j++) s += A4s[i * J + j] * xs[f * (J * CIN) + j * CIN + c];
        out[fbase * (J * CIN) + t] = s;
    }
}

// ---------------------------------------------------------------------------
extern "C" void kernel_launch(void* const* d_in, const int* in_sizes, int n_in,
                              void* d_out, int out_size, void* d_ws, size_t ws_size,
                              hipStream_t stream)
{
    const float* x  = (const float*)d_in[0];
    const float* A1 = (const float*)d_in[1];
    const float* W1 = (const float*)d_in[2];
    const float* b1 = (const float*)d_in[3];
    const float* A2 = (const float*)d_in[4];
    const float* W2 = (const float*)d_in[5];
    const float* b2 = (const float*)d_in[6];
    const float* A3 = (const float*)d_in[7];
    const float* W3 = (const float*)d_in[8];
    const float* b3 = (const float*)d_in[9];
    const float* A4 = (const float*)d_in[10];
    const float* W4 = (const float*)d_in[11];
    const float* b4 = (const float*)d_in[12];
    float* out = (float*)d_out;
    float* ws  = (float*)d_ws;

    const int NT = in_sizes[0] / (J * CIN);          // 65536
    const int nblocks = (NT + FPB - 1) / FPB;        // 32768 (NT divisible by FPB)

    gcn_precompute<<<1, 256, 0, stream>>>(A1, A2, A3, A4, W3, b2, b3, ws);
    gcn_fused<<<nblocks, 256, 0, stream>>>(x, W1, b1, W2, W4, b4, ws, out, W3);
}

// Round 2
// 394.905 us; speedup vs baseline: 1.5968x; 1.5968x over previous
//
#include <hip/hip_runtime.h>
#include <math.h>

#define J 25
#define CIN 3
#define HID 64
#define LAT 32
#define F 4                    // frames per block
#define NROW (F * J)           // 100 real rows
#define HS 72                  // Hs row stride (bf16), 144 B, 16B-aligned
#define US 40                  // Ut row stride (bf16), 80 B
#define VS 40
#define W2S 72
#define W3S 40
#define APS 40

// ws layout (floats): A1s[625] | App[625] | A4s[625] | bpp[64]
#define WS_A1  0
#define WS_APP 625
#define WS_A4  1250
#define WS_BPP 1875

using bf16x8 = __attribute__((ext_vector_type(8))) __bf16;
using f32x16 = __attribute__((ext_vector_type(16))) float;

// ---------------------------------------------------------------------------
// Precompute: row-softmax A1..A4; App = A3s@A2s; bpp = W3^T b2 + b3.
// ---------------------------------------------------------------------------
__global__ void gcn_precompute(const float* __restrict__ A1,
                               const float* __restrict__ A2,
                               const float* __restrict__ A3,
                               const float* __restrict__ A4,
                               const float* __restrict__ W3,
                               const float* __restrict__ b2,
                               const float* __restrict__ b3,
                               float* __restrict__ ws)
{
    __shared__ float A2s[J * J];
    __shared__ float A3s[J * J];
    const int t = threadIdx.x;

    if (t < 4 * J) {
        const int m = t / J, i = t % J;
        const float* Asrc = (m == 0) ? A1 : (m == 1) ? A2 : (m == 2) ? A3 : A4;
        float row[J];
        float mx = -1e30f;
        #pragma unroll
        for (int j = 0; j < J; j++) { row[j] = Asrc[i * J + j]; mx = fmaxf(mx, row[j]); }
        float s = 0.f;
        #pragma unroll
        for (int j = 0; j < J; j++) { row[j] = expf(row[j] - mx); s += row[j]; }
        const float inv = 1.f / s;
        if (m == 0) {
            #pragma unroll
            for (int j = 0; j < J; j++) ws[WS_A1 + i * J + j] = row[j] * inv;
        } else if (m == 1) {
            #pragma unroll
            for (int j = 0; j < J; j++) A2s[i * J + j] = row[j] * inv;
        } else if (m == 2) {
            #pragma unroll
            for (int j = 0; j < J; j++) A3s[i * J + j] = row[j] * inv;
        } else {
            #pragma unroll
            for (int j = 0; j < J; j++) ws[WS_A4 + i * J + j] = row[j] * inv;
        }
    }
    __syncthreads();

    for (int idx = t; idx < J * J; idx += blockDim.x) {
        const int i = idx / J, jj = idx % J;
        float s = 0.f;
        #pragma unroll
        for (int k = 0; k < J; k++) s += A3s[i * J + k] * A2s[k * J + jj];
        ws[WS_APP + idx] = s;
    }

    if (t < HID) {
        float s = b3[t];
        #pragma unroll
        for (int l = 0; l < LAT; l++) s += W3[l * HID + t] * b2[l];
        ws[WS_BPP + t] = s;
    }
}

// ---------------------------------------------------------------------------
// Fused main kernel. Per block: F=4 frames, 4 waves.
//   L1 (VALU fp32): y = A1s@x ; H = relu(y@W1+b1)      -> Hs bf16 [128 x HS]
//   L2 (MFMA):      U = H@W2                            -> Ut  bf16 [(f,l) x i]
//   mid (MFMA):     V = App@U  (batched over (f,l))     -> Vs  bf16 [(f,i') x l]
//   L3 (MFMA):      HD = relu(V@W3 + bpp)               -> Hs (reuse)
//   L4 (VALU fp32): p = HD@W4 ; out = A4s@p + b4
//
// mfma_f32_32x32x16_bf16 layouts (m74/m101-verified C/D; standard A/B):
//   A[m][k]: m=lane&31, k=8*(lane>>5)+j     (per 16-K step)
//   B[k][n]: n=lane&31, k=8*(lane>>5)+j
//   C/D:     col=lane&31, row=(reg&3)+8*(reg>>2)+4*(lane>>5)
// ---------------------------------------------------------------------------
__global__ __launch_bounds__(256, 2) void gcn_fused(
    const float* __restrict__ x,
    const float* __restrict__ W1, const float* __restrict__ b1,
    const float* __restrict__ W2, const float* __restrict__ W3,
    const float* __restrict__ W4, const float* __restrict__ b4,
    const float* __restrict__ ws,
    float* __restrict__ out)
{
    __shared__ __bf16 Hsb[128 * HS];     // H rows (f*25+i), k=d  (also HD)
    __shared__ __bf16 Ut[128 * US];      // rows (f*32+l), cols i (K for mid)
    __shared__ __bf16 Vsb[128 * VS];     // rows (f*25+i'), cols l
    __shared__ __bf16 W2t[32 * W2S];     // [l][d]
    __shared__ __bf16 W3t[64 * W3S];     // [d][l]
    __shared__ __bf16 Appb[32 * APS];    // padded 32x32, zeros outside 25x25
    __shared__ float A1s[J * J], A4s[J * J];
    __shared__ float xs[F * J * CIN], ys[F * J * CIN], ps[NROW * 4];
    __shared__ float W1s[CIN * HID], W4s[HID * CIN];
    __shared__ float b1s[HID], bpps[HID], b4s[CIN];

    const int t = threadIdx.x;
    const int lane = t & 63, wv = t >> 6;
    const int half = lane >> 5, ln = lane & 31;
    const long base = (long)blockIdx.x * (F * J * CIN);

    // ---------------- init: constants -> LDS (with bf16 conversion) ----------
    for (int i = t; i < J * J; i += 256) { A1s[i] = ws[WS_A1 + i]; A4s[i] = ws[WS_A4 + i]; }
    for (int i = t; i < 32 * 32; i += 256) {
        const int r = i >> 5, c = i & 31;
        const float v = (r < J && c < J) ? ws[WS_APP + r * J + c] : 0.f;
        Appb[r * APS + c] = (__bf16)v;
    }
    for (int i = t; i < HID * LAT; i += 256) {      // W2 [64][32] -> W2t[l][d]
        const int d = i >> 5, l = i & 31;
        W2t[l * W2S + d] = (__bf16)W2[i];
    }
    for (int i = t; i < LAT * HID; i += 256) {      // W3 [32][64] -> W3t[d][l]
        const int l = i >> 6, d = i & 63;
        W3t[d * W3S + l] = (__bf16)W3[i];
    }
    for (int i = t; i < CIN * HID; i += 256) W1s[i] = W1[i];
    for (int i = t; i < HID * CIN; i += 256) W4s[i] = W4[i];
    if (t < HID) { b1s[t] = b1[t]; bpps[t] = ws[WS_BPP + t]; }
    if (t < CIN) b4s[t] = b4[t];
    {   // zero Ut entirely: K-pad cols (i>=25) MUST be 0 for the mid GEMM
        int* uz = (int*)Ut;
        for (int i = t; i < 128 * US / 2; i += 256) uz[i] = 0;
    }
    for (int i = t; i < F * J * CIN; i += 256) xs[i] = x[base + i];
    __syncthreads();

    // ---------------- L1a: y = A1s @ x  (300 outputs) ------------------------
    for (int idx = t; idx < F * J * CIN; idx += 256) {
        const int f = idx / (J * CIN), rem = idx % (J * CIN);
        const int i = rem / CIN, c = rem % CIN;
        float s = 0.f;
        #pragma unroll
        for (int j = 0; j < J; j++) s += A1s[i * J + j] * xs[f * (J * CIN) + j * CIN + c];
        ys[idx] = s;
    }
    __syncthreads();

    // ---------------- L1b: H = relu(y@W1 + b1) -> bf16 -----------------------
    {
        const int d = t & 63, g = t >> 6;
        for (int R = g; R < NROW; R += 4) {
            float s = b1s[d] + ys[R * 3 + 0] * W1s[0 * HID + d]
                             + ys[R * 3 + 1] * W1s[1 * HID + d]
                             + ys[R * 3 + 2] * W1s[2 * HID + d];
            Hsb[R * HS + d] = (__bf16)fmaxf(s, 0.f);
        }
    }
    __syncthreads();

    // ---------------- L2 MFMA: U = H @ W2  (M=rows, K=64, N=32) --------------
    {
        const int m = 32 * wv + ln;
        const __bf16* Ar = &Hsb[m * HS + half * 8];
        const __bf16* Br = &W2t[ln * W2S + half * 8];
        f32x16 acc;
        #pragma unroll
        for (int z = 0; z < 16; z++) acc[z] = 0.f;
        #pragma unroll
        for (int ks = 0; ks < 4; ks++) {
            bf16x8 a = *(const bf16x8*)(Ar + ks * 16);
            bf16x8 b = *(const bf16x8*)(Br + ks * 16);
            acc = __builtin_amdgcn_mfma_f32_32x32x16_bf16(a, b, acc, 0, 0, 0);
        }
        #pragma unroll
        for (int reg = 0; reg < 16; reg++) {
            const int row32 = (reg & 3) + 8 * (reg >> 2) + 4 * half;
            const int r = 32 * wv + row32;
            if (r < NROW) {
                const int f = r / J, i = r - J * (r / J);
                Ut[(f * 32 + ln) * US + i] = (__bf16)acc[reg];   // transpose to K-major
            }
        }
    }
    __syncthreads();

    // ---------------- mid MFMA: V = App @ U  (wave wv = frame wv) ------------
    {
        const __bf16* Ar = &Appb[ln * APS + half * 8];
        const __bf16* Br = &Ut[(wv * 32 + ln) * US + half * 8];
        f32x16 acc;
        #pragma unroll
        for (int z = 0; z < 16; z++) acc[z] = 0.f;
        #pragma unroll
        for (int ks = 0; ks < 2; ks++) {
            bf16x8 a = *(const bf16x8*)(Ar + ks * 16);
            bf16x8 b = *(const bf16x8*)(Br + ks * 16);
            acc = __builtin_amdgcn_mfma_f32_32x32x16_bf16(a, b, acc, 0, 0, 0);
        }
        #pragma unroll
        for (int reg = 0; reg < 16; reg++) {
            const int row32 = (reg & 3) + 8 * (reg >> 2) + 4 * half;
            if (row32 < J) Vsb[(wv * J + row32) * VS + ln] = (__bf16)acc[reg];
        }
    }
    __syncthreads();

    // ---------------- L3 MFMA: HD = relu(V@W3 + bpp)  (K=32, N=64) -----------
    {
        const int m = 32 * wv + ln;
        const __bf16* Ar = &Vsb[m * VS + half * 8];
        const __bf16* B0 = &W3t[ln * W3S + half * 8];
        const __bf16* B1 = &W3t[(32 + ln) * W3S + half * 8];
        f32x16 acc0, acc1;
        #pragma unroll
        for (int z = 0; z < 16; z++) { acc0[z] = 0.f; acc1[z] = 0.f; }
        #pragma unroll
        for (int ks = 0; ks < 2; ks++) {
            bf16x8 a = *(const bf16x8*)(Ar + ks * 16);
            acc0 = __builtin_amdgcn_mfma_f32_32x32x16_bf16(a, *(const bf16x8*)(B0 + ks * 16), acc0, 0, 0, 0);
            acc1 = __builtin_amdgcn_mfma_f32_32x32x16_bf16(a, *(const bf16x8*)(B1 + ks * 16), acc1, 0, 0, 0);
        }
        #pragma unroll
        for (int reg = 0; reg < 16; reg++) {
            const int row32 = (reg & 3) + 8 * (reg >> 2) + 4 * half;
            const int r = 32 * wv + row32;
            if (r < NROW) {
                Hsb[r * HS + ln]      = (__bf16)fmaxf(acc0[reg] + bpps[ln], 0.f);
                Hsb[r * HS + 32 + ln] = (__bf16)fmaxf(acc1[reg] + bpps[32 + ln], 0.f);
            }
        }
    }
    __syncthreads();

    // ---------------- L4a: p = HD @ W4  (K=64, N=3, VALU) ---------------------
    for (int idx = t; idx < NROW * CIN; idx += 256) {
        const int r = idx / 3, c = idx % 3;
        float s = 0.f;
        #pragma unroll
        for (int d8 = 0; d8 < 8; d8++) {
            bf16x8 hv = *(const bf16x8*)&Hsb[r * HS + d8 * 8];
            #pragma unroll
            for (int j = 0; j < 8; j++) s += (float)hv[j] * W4s[(d8 * 8 + j) * CIN + c];
        }
        ps[r * 4 + c] = s;
    }
    __syncthreads();

    // ---------------- L4b: out = A4s @ p + b4 --------------------------------
    for (int idx = t; idx < F * J * CIN; idx += 256) {
        const int f = idx / (J * CIN), rem = idx % (J * CIN);
        const int i = rem / CIN, c = rem % CIN;
        float s = b4s[c];
        #pragma unroll
        for (int j = 0; j < J; j++) s += A4s[i * J + j] * ps[(f * J + j) * 4 + c];
        out[base + idx] = s;
    }
}

// ---------------------------------------------------------------------------
extern "C" void kernel_launch(void* const* d_in, const int* in_sizes, int n_in,
                              void* d_out, int out_size, void* d_ws, size_t ws_size,
                              hipStream_t stream)
{
    const float* x  = (const float*)d_in[0];
    const float* A1 = (const float*)d_in[1];
    const float* W1 = (const float*)d_in[2];
    const float* b1 = (const float*)d_in[3];
    const float* A2 = (const float*)d_in[4];
    const float* W2 = (const float*)d_in[5];
    const float* b2 = (const float*)d_in[6];
    const float* A3 = (const float*)d_in[7];
    const float* W3 = (const float*)d_in[8];
    const float* b3 = (const float*)d_in[9];
    const float* A4 = (const float*)d_in[10];
    const float* W4 = (const float*)d_in[11];
    const float* b4 = (const float*)d_in[12];
    float* out = (float*)d_out;
    float* ws  = (float*)d_ws;

    const int NT = in_sizes[0] / (J * CIN);          // 65536
    const int nblocks = NT / F;                      // 16384

    gcn_precompute<<<1, 256, 0, stream>>>(A1, A2, A3, A4, W3, b2, b3, ws);
    gcn_fused<<<nblocks, 256, 0, stream>>>(x, W1, b1, W2, W3, W4, b4, ws, out);
}

// Round 3
// 242.210 us; speedup vs baseline: 2.6034x; 1.6304x over previous
//
#include <hip/hip_runtime.h>
#include <math.h>

#define J 25
#define NJC 75             // J * CIN
#define F 10               // frames per block = waves per block
#define NTHREADS 640

// ws float offsets (written by gcn_precompute every launch)
#define WS_A1  0
#define WS_APP 625
#define WS_A4  1250
#define WS_BPP 1875

using bf16x4 = __attribute__((ext_vector_type(4))) __bf16;
using bf16x8 = __attribute__((ext_vector_type(8))) __bf16;
using f32x4  = __attribute__((ext_vector_type(4))) float;
using f32x16 = __attribute__((ext_vector_type(16))) float;

__device__ inline bf16x8 zero8() {
    bf16x8 z;
    #pragma unroll
    for (int j = 0; j < 8; j++) z[j] = (__bf16)0.f;
    return z;
}

// ---------------------------------------------------------------------------
// Precompute: row-softmax A1..A4; App = A3s@A2s; bpp = W3^T b2 + b3.
// ---------------------------------------------------------------------------
__global__ void gcn_precompute(const float* __restrict__ A1,
                               const float* __restrict__ A2,
                               const float* __restrict__ A3,
                               const float* __restrict__ A4,
                               const float* __restrict__ W3,
                               const float* __restrict__ b2,
                               const float* __restrict__ b3,
                               float* __restrict__ ws)
{
    __shared__ float A2s[J * J];
    __shared__ float A3s[J * J];
    const int t = threadIdx.x;

    if (t < 4 * J) {
        const int m = t / J, i = t % J;
        const float* Asrc = (m == 0) ? A1 : (m == 1) ? A2 : (m == 2) ? A3 : A4;
        float row[J];
        float mx = -1e30f;
        #pragma unroll
        for (int j = 0; j < J; j++) { row[j] = Asrc[i * J + j]; mx = fmaxf(mx, row[j]); }
        float s = 0.f;
        #pragma unroll
        for (int j = 0; j < J; j++) { row[j] = expf(row[j] - mx); s += row[j]; }
        const float inv = 1.f / s;
        if (m == 0) {
            #pragma unroll
            for (int j = 0; j < J; j++) ws[WS_A1 + i * J + j] = row[j] * inv;
        } else if (m == 1) {
            #pragma unroll
            for (int j = 0; j < J; j++) A2s[i * J + j] = row[j] * inv;
        } else if (m == 2) {
            #pragma unroll
            for (int j = 0; j < J; j++) A3s[i * J + j] = row[j] * inv;
        } else {
            #pragma unroll
            for (int j = 0; j < J; j++) ws[WS_A4 + i * J + j] = row[j] * inv;
        }
    }
    __syncthreads();

    for (int idx = t; idx < J * J; idx += blockDim.x) {
        const int i = idx / J, jj = idx % J;
        float s = 0.f;
        #pragma unroll
        for (int k = 0; k < J; k++) s += A3s[i * J + k] * A2s[k * J + jj];
        ws[WS_APP + idx] = s;
    }

    if (t < 64) {
        float s = b3[t];
        #pragma unroll
        for (int l = 0; l < 32; l++) s += W3[l * 64 + t] * b2[l];
        ws[WS_BPP + t] = s;
    }
}

// ---------------------------------------------------------------------------
// Fused kernel. One frame per WAVE; all inter-stage LDS traffic is intra-wave
// (DS ops in-order per wave) -> zero barriers after weight staging.
//
// Frag layout (both A and B operands), bf16:  addr = blk*STRIDE + row*8 + (k&7),
// blk = k>>3.  Weights use STRIDE=256 (read-only, 2-way free); per-frame
// scratch uses STRIDE=264 (528B) to spread b16 scatter writes across banks.
//
// mfma_f32_32x32x16_bf16 (R2-verified):
//   A[m][k]: m=lane&31, k=8*(lane>>5)+j+16*ks
//   B[k][n]: n=lane&31, k=8*(lane>>5)+j+16*ks
//   C/D:     col=lane&31, row=(reg&3)+8*(reg>>2)+4*(lane>>5)
//
// Pipeline (per wave, frame f):
//   P1: Y^T(c x i)   = X^T_aug @ A1T          (ones-row c=3 -> bias slot)
//   P2: H^T(d x i)   = relu(W1T_aug @ Y^T)    (b1 folded via c=3 col)
//   P3: U^T(l x i)   = W2T @ H^T              -> scatter as mid B-frag
//   P4: V (i' x l)   = Appb @ U               -> scatter as V^T B-frag
//   P5: HD^T(d x i') = relu(W3T @ V^T + bpp)  -> b64-packed A-frag for L4a
//   P6: P (i' x c)   = HD @ W4c               -> b64-packed out B-frag
//   P7: out          = A4b @ P + b4           -> LDS -> coalesced store
// ---------------------------------------------------------------------------
__global__ __launch_bounds__(NTHREADS, 4) void gcn_fused(
    const float* __restrict__ x,
    const float* __restrict__ W1, const float* __restrict__ b1,
    const float* __restrict__ W2, const float* __restrict__ W3,
    const float* __restrict__ W4, const float* __restrict__ b4,
    const float* __restrict__ ws,
    float* __restrict__ out, const int NT)
{
    __shared__ __bf16 A1T[1024];    // B-frag [k=j][n=i], zero-padded
    __shared__ __bf16 Appb[1024];   // A-frag [m=i'][k=j], zero-padded
    __shared__ __bf16 A4b[1024];    // A-frag [m=i''][k=j], zero-padded
    __shared__ __bf16 W2T[2048];    // A-frag [m=l][k=d]
    __shared__ __bf16 W3T[2048];    // A-frag [m=d][k=l], 2 M-tiles
    __shared__ __bf16 W1T[512];     // A-frag [m=d][k=c(4)], 2 M-tiles, b1 in c=3
    __shared__ __bf16 W4c[192];     // compact [n=c][k=d]
    __shared__ float  bpps[64], b4s[4];
    __shared__ __bf16 RA[F * 1056]; // per-frame scratch A (2112B, stride-264 blocks)
    __shared__ __bf16 RB[F * 1056]; // per-frame scratch B

    const int t = threadIdx.x;

    // ---------------- weight staging (bf16 conversion) ----------------------
    for (int i = t; i < 1024; i += NTHREADS) {
        const int b = i >> 8, n = (i >> 3) & 31, jj = i & 7, j = 8 * b + jj;
        const bool ok = (j < J) && (n < J);
        A1T[i]  = (__bf16)(ok ? ws[WS_A1  + n * J + j] : 0.f);  // A1[i=n][j]
        Appb[i] = (__bf16)(ok ? ws[WS_APP + n * J + j] : 0.f);  // App[m=n][j]
        A4b[i]  = (__bf16)(ok ? ws[WS_A4  + n * J + j] : 0.f);
    }
    for (int i = t; i < 2048; i += NTHREADS) {
        const int b = i >> 8, m = (i >> 3) & 31, jj = i & 7;
        W2T[i] = (__bf16)W2[(8 * b + jj) * 32 + m];             // [m=l][k=d]
        const int tt = i >> 10, r = i & 1023;
        const int b3 = r >> 8, m3 = (r >> 3) & 31, j3 = r & 7;
        W3T[i] = (__bf16)W3[(8 * b3 + j3) * 64 + tt * 32 + m3]; // [m=d][k=l]
    }
    for (int i = t; i < 512; i += NTHREADS) {
        const int tt = i >> 8, m = (i >> 3) & 31, c = i & 7, d = tt * 32 + m;
        float v = 0.f;
        if (c < 3) v = W1[c * 64 + d];
        else if (c == 3) v = b1[d];
        W1T[i] = (__bf16)v;
    }
    for (int i = t; i < 192; i += NTHREADS)
        W4c[i] = (__bf16)W4[(i & 63) * 3 + (i >> 6)];           // [n=c][k=d]
    if (t < 64) bpps[t] = ws[WS_BPP + t];
    if (t < 4)  b4s[t] = (t < 3) ? b4[t] : 0.f;
    __syncthreads();

    // ---------------- per-wave pipeline --------------------------------------
    const int w = t >> 6, lane = t & 63, ln = lane & 31, half = lane >> 5;
    const int f = blockIdx.x * F + w;
    if (f >= NT) return;

    __bf16* ra = &RA[w * 1056];
    __bf16* rb = &RB[w * 1056];
    float* xs = (float*)rb;                     // 75 floats

    for (int i = lane; i < NJC; i += 64) xs[i] = x[(long)f * NJC + i];

    // ---- P1: Y^T = X^T_aug @ A1T (M=c rows 0..3, N=i, K=j pad32)
    bf16x8 xa[2];
    #pragma unroll
    for (int ks = 0; ks < 2; ks++) {
        #pragma unroll
        for (int jj = 0; jj < 8; jj++) {
            const int k = ks * 16 + half * 8 + jj;
            float v = 0.f;
            if (ln == 3) v = 1.f;                        // ones row -> bias slot
            else if (ln < 3 && k < J) v = xs[k * 3 + ln];
            xa[ks][jj] = (__bf16)v;
        }
    }
    f32x16 accY;
    #pragma unroll
    for (int z = 0; z < 16; z++) accY[z] = 0.f;
    #pragma unroll
    for (int ks = 0; ks < 2; ks++) {
        bf16x8 bb = *(const bf16x8*)&A1T[(half + 2 * ks) * 256 + ln * 8];
        accY = __builtin_amdgcn_mfma_f32_32x32x16_bf16(xa[ks], bb, accY, 0, 0, 0);
    }
    if (half == 0) {                                     // rows 0..3 (c + ones)
        bf16x4 p;
        #pragma unroll
        for (int r2 = 0; r2 < 4; r2++) p[r2] = (__bf16)accY[r2];
        *(bf16x4*)&ra[ln * 8] = p;                       // Y^T [b=0][n=i][jj=c]
    }

    // ---- P2: H^T = relu(W1T_aug @ Y^T)  (M=d 2 tiles, N=i, K=16)
    bf16x8 yb;
    {
        bf16x4 lo;
        #pragma unroll
        for (int jj = 0; jj < 4; jj++) lo[jj] = (__bf16)0.f;
        if (half == 0) lo = *(const bf16x4*)&ra[ln * 8];
        #pragma unroll
        for (int jj = 0; jj < 4; jj++) {
            yb[jj] = (half == 0) ? lo[jj] : (__bf16)0.f;
            yb[4 + jj] = (__bf16)0.f;
        }
    }
    #pragma unroll
    for (int tt = 0; tt < 2; tt++) {
        bf16x8 a = zero8();
        if (half == 0) a = *(const bf16x8*)&W1T[tt * 256 + ln * 8];
        f32x16 acc;
        #pragma unroll
        for (int z = 0; z < 16; z++) acc[z] = 0.f;
        acc = __builtin_amdgcn_mfma_f32_32x32x16_bf16(a, yb, acc, 0, 0, 0);
        #pragma unroll
        for (int g = 0; g < 4; g++) {                    // d = tt*32+8g+4h+r2
            bf16x4 p;
            #pragma unroll
            for (int r2 = 0; r2 < 4; r2++) p[r2] = (__bf16)fmaxf(acc[4 * g + r2], 0.f);
            const int b = tt * 4 + g;
            __bf16* dst = (b < 4) ? ra : rb;
            *(bf16x4*)&dst[(b & 3) * 264 + ln * 8 + 4 * half] = p;
        }
    }

    // ---- P3: U^T = W2T @ H^T  (M=l, N=i, K=64)
    f32x16 accU;
    #pragma unroll
    for (int z = 0; z < 16; z++) accU[z] = 0.f;
    #pragma unroll
    for (int ks = 0; ks < 4; ks++) {
        const int b = half + 2 * ks;
        bf16x8 a  = *(const bf16x8*)&W2T[b * 256 + ln * 8];
        bf16x8 bb = *(const bf16x8*)&((b < 4) ? ra : rb)[(b & 3) * 264 + ln * 8];
        accU = __builtin_amdgcn_mfma_f32_32x32x16_bf16(a, bb, accU, 0, 0, 0);
    }
    #pragma unroll
    for (int r = 0; r < 16; r++) {                       // U B-frag [b=j>>3][n=l][jj]
        const int row = (r & 3) + 8 * (r >> 2) + 4 * half;   // l
        ra[(ln >> 3) * 264 + row * 8 + (ln & 7)] = (__bf16)accU[r];  // j = ln
    }

    // ---- P4: V = Appb @ U  (M=i', N=l, K=j pad32)
    f32x16 accV;
    #pragma unroll
    for (int z = 0; z < 16; z++) accV[z] = 0.f;
    #pragma unroll
    for (int ks = 0; ks < 2; ks++) {
        bf16x8 a  = *(const bf16x8*)&Appb[(half + 2 * ks) * 256 + ln * 8];
        bf16x8 bb = *(const bf16x8*)&ra[(half + 2 * ks) * 264 + ln * 8];
        accV = __builtin_amdgcn_mfma_f32_32x32x16_bf16(a, bb, accV, 0, 0, 0);
    }
    #pragma unroll
    for (int r = 0; r < 16; r++) {                       // V^T B-frag [b=l>>3][n=i'][jj]
        const int row = (r & 3) + 8 * (r >> 2) + 4 * half;   // i'
        rb[(ln >> 3) * 264 + row * 8 + (ln & 7)] = (__bf16)accV[r];  // l = ln
    }

    // ---- P5: HD^T = relu(W3T @ V^T + bpp)  (M=d 2 tiles, N=i', K=32)
    #pragma unroll
    for (int tt = 0; tt < 2; tt++) {
        f32x16 acc;
        #pragma unroll
        for (int z = 0; z < 16; z++) acc[z] = 0.f;
        #pragma unroll
        for (int ks = 0; ks < 2; ks++) {
            bf16x8 a  = *(const bf16x8*)&W3T[tt * 1024 + (half + 2 * ks) * 256 + ln * 8];
            bf16x8 bb = *(const bf16x8*)&rb[(half + 2 * ks) * 264 + ln * 8];
            acc = __builtin_amdgcn_mfma_f32_32x32x16_bf16(a, bb, acc, 0, 0, 0);
        }
        #pragma unroll
        for (int g = 0; g < 4; g++) {
            f32x4 bias = *(const f32x4*)&bpps[tt * 32 + 8 * g + 4 * half];
            bf16x4 p;
            #pragma unroll
            for (int r2 = 0; r2 < 4; r2++)
                p[r2] = (__bf16)fmaxf(acc[4 * g + r2] + bias[r2], 0.f);
            const int b = tt * 4 + g;                    // HD A-frag block
            __bf16* dst = (b < 4) ? ra : rb;
            *(bf16x4*)&dst[(b & 3) * 264 + ln * 8 + 4 * half] = p;
        }
    }

    // ---- P6: P = HD @ W4c  (M=i', N=c, K=64)
    f32x16 accP;
    #pragma unroll
    for (int z = 0; z < 16; z++) accP[z] = 0.f;
    #pragma unroll
    for (int ks = 0; ks < 4; ks++) {
        const int b = half + 2 * ks;
        bf16x8 a = *(const bf16x8*)&((b < 4) ? ra : rb)[(b & 3) * 264 + ln * 8];
        bf16x8 bb = zero8();
        if (ln < 3) bb = *(const bf16x8*)&W4c[ln * 64 + b * 8];
        accP = __builtin_amdgcn_mfma_f32_32x32x16_bf16(a, bb, accP, 0, 0, 0);
    }
    #pragma unroll
    for (int g = 0; g < 4; g++) {                        // P B-frag [b=i'>>3][n=c][jj]
        bf16x4 p;
        #pragma unroll
        for (int r2 = 0; r2 < 4; r2++) p[r2] = (__bf16)accP[4 * g + r2];
        *(bf16x4*)&ra[g * 264 + ln * 8 + 4 * half] = p;
    }

    // ---- P7: out = A4b @ P + b4
    f32x16 accO;
    #pragma unroll
    for (int z = 0; z < 16; z++) accO[z] = 0.f;
    #pragma unroll
    for (int ks = 0; ks < 2; ks++) {
        bf16x8 a  = *(const bf16x8*)&A4b[(half + 2 * ks) * 256 + ln * 8];
        bf16x8 bb = *(const bf16x8*)&ra[(half + 2 * ks) * 264 + ln * 8];
        accO = __builtin_amdgcn_mfma_f32_32x32x16_bf16(a, bb, accO, 0, 0, 0);
    }
    float* outs = (float*)rb;                            // 75 floats (HD-hi dead)
    if (ln < 3) {
        const float b4v = b4s[ln];
        #pragma unroll
        for (int r = 0; r < 16; r++) {
            const int row = (r & 3) + 8 * (r >> 2) + 4 * half;
            if (row < J) outs[row * 3 + ln] = accO[r] + b4v;
        }
    }
    for (int i = lane; i < NJC; i += 64) out[(long)f * NJC + i] = outs[i];
}

// ---------------------------------------------------------------------------
extern "C" void kernel_launch(void* const* d_in, const int* in_sizes, int n_in,
                              void* d_out, int out_size, void* d_ws, size_t ws_size,
                              hipStream_t stream)
{
    const float* x  = (const float*)d_in[0];
    const float* A1 = (const float*)d_in[1];
    const float* W1 = (const float*)d_in[2];
    const float* b1 = (const float*)d_in[3];
    const float* A2 = (const float*)d_in[4];
    const float* W2 = (const float*)d_in[5];
    const float* b2 = (const float*)d_in[6];
    const float* A3 = (const float*)d_in[7];
    const float* W3 = (const float*)d_in[8];
    const float* b3 = (const float*)d_in[9];
    const float* A4 = (const float*)d_in[10];
    const float* W4 = (const float*)d_in[11];
    const float* b4 = (const float*)d_in[12];
    float* out = (float*)d_out;
    float* ws  = (float*)d_ws;

    const int NT = in_sizes[0] / NJC;                 // 65536
    const int nblocks = (NT + F - 1) / F;             // 6554

    gcn_precompute<<<1, 256, 0, stream>>>(A1, A2, A3, A4, W3, b2, b3, ws);
    gcn_fused<<<nblocks, NTHREADS, 0, stream>>>(x, W1, b1, W2, W3, W4, b4, ws, out, NT);
}

// Round 4
// 196.541 us; speedup vs baseline: 3.2083x; 1.2324x over previous
//
#include <hip/hip_runtime.h>
#include <math.h>

#define J 25
#define NJC 75             // J * CIN
#define F 8                // frames per block = waves per block
#define NTHREADS 512

using bf16x4 = __attribute__((ext_vector_type(4))) __bf16;
using bf16x8 = __attribute__((ext_vector_type(8))) __bf16;
using f32x4  = __attribute__((ext_vector_type(4))) float;
using f32x16 = __attribute__((ext_vector_type(16))) float;

__device__ inline bf16x8 zero8() {
    bf16x8 z;
    #pragma unroll
    for (int j = 0; j < 8; j++) z[j] = (__bf16)0.f;
    return z;
}

// ---------------------------------------------------------------------------
// Single fused kernel. Staging phase (3 barriers): per-block redundant
// softmax(A1..A4), App = A3s@A2s, bpp = W3^T b2 + b3 (fp32 temps aliased over
// the per-wave scratch), then frag-layout conversion to bf16. Pipeline phase:
// one frame per WAVE, all inter-stage LDS traffic intra-wave (DS ops in-order
// per wave) -> zero barriers.
//
// Frag addressing (A and B operands), bf16: addr = blk*STRIDE + row*8 + (k&7),
// blk = k>>3. Weights STRIDE=256; per-frame scratch STRIDE=264.
//
// mfma_f32_32x32x16_bf16 (R2/R3-verified):
//   A[m][k]: m=lane&31, k=8*(lane>>5)+j+16*ks
//   B[k][n]: n=lane&31, k=8*(lane>>5)+j+16*ks
//   C/D:     col=lane&31, row=(reg&3)+8*(reg>>2)+4*(lane>>5)
//
// Pipeline (per wave, frame f):
//   P1: Y^T(c x i)   = X^T_aug @ A1T          (ones-row c=3 -> bias slot)
//   P2: H^T(d x i)   = relu(W1T_aug @ Y^T)    (Y^T consumed IN-REGISTER)
//   P3: U^T(l x i)   = W2T @ H^T              -> scatter as mid B-frag
//   P4: V (i' x l)   = Appb @ U               -> scatter as V^T B-frag
//   P5: HD^T(d x i') = relu(W3T @ V^T + bpp)  -> b64-packed A-frag
//   P6: P (i' x c)   = HD @ W4c               -> b64-packed B-frag
//   P7: out          = A4b @ P + b4           -> direct global scatter stores
// ---------------------------------------------------------------------------
__global__ __launch_bounds__(NTHREADS, 6) void gcn_fused(
    const float* __restrict__ x,
    const float* __restrict__ A1, const float* __restrict__ W1, const float* __restrict__ b1,
    const float* __restrict__ A2, const float* __restrict__ W2, const float* __restrict__ b2,
    const float* __restrict__ A3, const float* __restrict__ W3, const float* __restrict__ b3,
    const float* __restrict__ A4, const float* __restrict__ W4, const float* __restrict__ b4,
    float* __restrict__ out, const int NT)
{
    __shared__ __bf16 A1T[1024];    // B-frag [k=j][n=i], zero-padded
    __shared__ __bf16 Appb[1024];   // A-frag [m=i'][k=j], zero-padded
    __shared__ __bf16 A4b[1024];    // A-frag [m=i''][k=j], zero-padded
    __shared__ __bf16 W2T[2048];    // A-frag [m=l][k=d]
    __shared__ __bf16 W3T[2048];    // A-frag [m=d][k=l], 2 M-tiles
    __shared__ __bf16 W1T[512];     // A-frag [m=d][k=c(8)], 2 M-tiles, b1 in c=3
    __shared__ __bf16 W4c[192];     // compact [n=c][k=d]
    __shared__ float  bpps[64], b4s[4];
    __align__(16) __shared__ __bf16 RA[F * 1056]; // per-frame scratch A (2112B)
    __align__(16) __shared__ __bf16 RB[F * 1056]; // per-frame scratch B

    const int t = threadIdx.x;

    // ================= staging phase =========================================
    // fp32 temps aliased over RA (4224 floats available, we use 3125):
    float* T  = (float*)RA;
    float* T0 = T;               // softmax(A1) [625]
    float* T1 = T + 625;         // softmax(A2)
    float* T2 = T + 1250;        // softmax(A3)
    float* T3 = T + 1875;        // softmax(A4)
    float* T4 = T + 2500;        // App = T2 @ T1 [625]

    if (t < 100) {
        const int m = t / J, i = t % J;
        const float* Asrc = (m == 0) ? A1 : (m == 1) ? A2 : (m == 2) ? A3 : A4;
        float row[J];
        float mx = -1e30f;
        #pragma unroll
        for (int j = 0; j < J; j++) { row[j] = Asrc[i * J + j]; mx = fmaxf(mx, row[j]); }
        float s = 0.f;
        #pragma unroll
        for (int j = 0; j < J; j++) { row[j] = __expf(row[j] - mx); s += row[j]; }
        const float inv = 1.f / s;
        float* dst = T + m * 625 + i * J;
        #pragma unroll
        for (int j = 0; j < J; j++) dst[j] = row[j] * inv;
    }
    if (t < 64) {                               // bpp (no dependency on T)
        float s = b3[t];
        #pragma unroll
        for (int l = 0; l < 32; l++) s += W3[l * 64 + t] * b2[l];
        bpps[t] = s;
    }
    if (t < 4) b4s[t] = (t < 3) ? b4[t] : 0.f;
    __syncthreads();

    for (int idx = t; idx < 625; idx += NTHREADS) {   // App = A3s @ A2s
        const int i = idx / J, jj = idx % J;
        float s = 0.f;
        #pragma unroll
        for (int k = 0; k < J; k++) s += T2[i * J + k] * T1[k * J + jj];
        T4[idx] = s;
    }
    __syncthreads();

    // frag conversions (read T*, write separate LDS regions)
    for (int i = t; i < 1024; i += NTHREADS) {
        const int b = i >> 8, n = (i >> 3) & 31, jj = i & 7, j = 8 * b + jj;
        const bool ok = (j < J) && (n < J);
        A1T[i]  = (__bf16)(ok ? T0[n * J + j] : 0.f);
        Appb[i] = (__bf16)(ok ? T4[n * J + j] : 0.f);
        A4b[i]  = (__bf16)(ok ? T3[n * J + j] : 0.f);
    }
    for (int i = t; i < 2048; i += NTHREADS) {
        const int b = i >> 8, m = (i >> 3) & 31, jj = i & 7;
        W2T[i] = (__bf16)W2[(8 * b + jj) * 32 + m];             // [m=l][k=d]
        const int tt = i >> 10, r = i & 1023;
        const int b3i = r >> 8, m3 = (r >> 3) & 31, j3 = r & 7;
        W3T[i] = (__bf16)W3[(8 * b3i + j3) * 64 + tt * 32 + m3]; // [m=d][k=l]
    }
    for (int i = t; i < 512; i += NTHREADS) {
        const int tt = i >> 8, m = (i >> 3) & 31, c = i & 7, d = tt * 32 + m;
        float v = 0.f;
        if (c < 3) v = W1[c * 64 + d];
        else if (c == 3) v = b1[d];
        W1T[i] = (__bf16)v;
    }
    for (int i = t; i < 192; i += NTHREADS)
        W4c[i] = (__bf16)W4[(i & 63) * 3 + (i >> 6)];           // [n=c][k=d]
    __syncthreads();

    // ================= per-wave pipeline =====================================
    const int w = t >> 6, lane = t & 63, ln = lane & 31, half = lane >> 5;
    const int f = blockIdx.x * F + w;
    if (f >= NT) return;

    __bf16* ra = &RA[w * 1056];
    __bf16* rb = &RB[w * 1056];

    // ---- x staging: transposed xT[c][j] (stride 32), zero-padded
    float* xT = (float*)rb;
    for (int i = lane; i < 96; i += 64) xT[i] = 0.f;
    for (int i = lane; i < NJC; i += 64) {
        const float v = x[(long)f * NJC + i];
        xT[(i % 3) * 32 + (i / 3)] = v;
    }

    // ---- P1: Y^T = X^T_aug @ A1T  (M=c rows 0..3, N=i, K=j pad32)
    bf16x8 xa[2];
    #pragma unroll
    for (int ks = 0; ks < 2; ks++) {
        f32x4 v0, v1;
        #pragma unroll
        for (int z = 0; z < 4; z++) { v0[z] = 0.f; v1[z] = 0.f; }
        if (ln < 3) {
            v0 = *(const f32x4*)&xT[ln * 32 + ks * 16 + half * 8];
            v1 = *(const f32x4*)&xT[ln * 32 + ks * 16 + half * 8 + 4];
        }
        #pragma unroll
        for (int jj = 0; jj < 4; jj++) {
            xa[ks][jj]     = (ln == 3) ? (__bf16)1.f : (__bf16)v0[jj];
            xa[ks][4 + jj] = (ln == 3) ? (__bf16)1.f : (__bf16)v1[jj];
        }
    }
    f32x16 accY;
    #pragma unroll
    for (int z = 0; z < 16; z++) accY[z] = 0.f;
    #pragma unroll
    for (int ks = 0; ks < 2; ks++) {
        bf16x8 bb = *(const bf16x8*)&A1T[(half + 2 * ks) * 256 + ln * 8];
        accY = __builtin_amdgcn_mfma_f32_32x32x16_bf16(xa[ks], bb, accY, 0, 0, 0);
    }

    // ---- P2: H^T = relu(W1T_aug @ Y^T) — Y^T consumed in-register:
    // C(lane=i, half0, regs 0..3 = c) == B-frag(lane n=i, k=c in j=0..3, half0)
    bf16x8 yb;
    #pragma unroll
    for (int jj = 0; jj < 8; jj++)
        yb[jj] = (half == 0 && jj < 4) ? (__bf16)accY[jj] : (__bf16)0.f;
    #pragma unroll
    for (int tt = 0; tt < 2; tt++) {
        bf16x8 a = zero8();
        if (half == 0) a = *(const bf16x8*)&W1T[tt * 256 + ln * 8];
        f32x16 acc;
        #pragma unroll
        for (int z = 0; z < 16; z++) acc[z] = 0.f;
        acc = __builtin_amdgcn_mfma_f32_32x32x16_bf16(a, yb, acc, 0, 0, 0);
        #pragma unroll
        for (int g = 0; g < 4; g++) {                    // d = tt*32+8g+4h+r2
            bf16x4 p;
            #pragma unroll
            for (int r2 = 0; r2 < 4; r2++) p[r2] = (__bf16)fmaxf(acc[4 * g + r2], 0.f);
            const int b = tt * 4 + g;
            __bf16* dst = (b < 4) ? ra : rb;
            *(bf16x4*)&dst[(b & 3) * 264 + ln * 8 + 4 * half] = p;
        }
    }

    // ---- P3: U^T = W2T @ H^T  (M=l, N=i, K=64)
    f32x16 accU;
    #pragma unroll
    for (int z = 0; z < 16; z++) accU[z] = 0.f;
    #pragma unroll
    for (int ks = 0; ks < 4; ks++) {
        const int b = half + 2 * ks;
        bf16x8 a  = *(const bf16x8*)&W2T[b * 256 + ln * 8];
        bf16x8 bb = *(const bf16x8*)&((b < 4) ? ra : rb)[(b & 3) * 264 + ln * 8];
        accU = __builtin_amdgcn_mfma_f32_32x32x16_bf16(a, bb, accU, 0, 0, 0);
    }
    #pragma unroll
    for (int r = 0; r < 16; r++) {                       // U B-frag [b=j>>3][n=l][jj]
        const int row = (r & 3) + 8 * (r >> 2) + 4 * half;   // l
        ra[(ln >> 3) * 264 + row * 8 + (ln & 7)] = (__bf16)accU[r];  // j = ln
    }

    // ---- P4: V = Appb @ U  (M=i', N=l, K=j pad32)
    f32x16 accV;
    #pragma unroll
    for (int z = 0; z < 16; z++) accV[z] = 0.f;
    #pragma unroll
    for (int ks = 0; ks < 2; ks++) {
        bf16x8 a  = *(const bf16x8*)&Appb[(half + 2 * ks) * 256 + ln * 8];
        bf16x8 bb = *(const bf16x8*)&ra[(half + 2 * ks) * 264 + ln * 8];
        accV = __builtin_amdgcn_mfma_f32_32x32x16_bf16(a, bb, accV, 0, 0, 0);
    }
    #pragma unroll
    for (int r = 0; r < 16; r++) {                       // V^T B-frag [b=l>>3][n=i'][jj]
        const int row = (r & 3) + 8 * (r >> 2) + 4 * half;   // i'
        rb[(ln >> 3) * 264 + row * 8 + (ln & 7)] = (__bf16)accV[r];  // l = ln
    }

    // ---- P5: HD^T = relu(W3T @ V^T + bpp)  (M=d 2 tiles, N=i', K=32)
    #pragma unroll
    for (int tt = 0; tt < 2; tt++) {
        f32x16 acc;
        #pragma unroll
        for (int z = 0; z < 16; z++) acc[z] = 0.f;
        #pragma unroll
        for (int ks = 0; ks < 2; ks++) {
            bf16x8 a  = *(const bf16x8*)&W3T[tt * 1024 + (half + 2 * ks) * 256 + ln * 8];
            bf16x8 bb = *(const bf16x8*)&rb[(half + 2 * ks) * 264 + ln * 8];
            acc = __builtin_amdgcn_mfma_f32_32x32x16_bf16(a, bb, acc, 0, 0, 0);
        }
        #pragma unroll
        for (int g = 0; g < 4; g++) {
            f32x4 bias = *(const f32x4*)&bpps[tt * 32 + 8 * g + 4 * half];
            bf16x4 p;
            #pragma unroll
            for (int r2 = 0; r2 < 4; r2++)
                p[r2] = (__bf16)fmaxf(acc[4 * g + r2] + bias[r2], 0.f);
            const int b = tt * 4 + g;                    // HD A-frag block
            __bf16* dst = (b < 4) ? ra : rb;
            *(bf16x4*)&dst[(b & 3) * 264 + ln * 8 + 4 * half] = p;
        }
    }

    // ---- P6: P = HD @ W4c  (M=i', N=c, K=64)
    f32x16 accP;
    #pragma unroll
    for (int z = 0; z < 16; z++) accP[z] = 0.f;
    #pragma unroll
    for (int ks = 0; ks < 4; ks++) {
        const int b = half + 2 * ks;
        bf16x8 a = *(const bf16x8*)&((b < 4) ? ra : rb)[(b & 3) * 264 + ln * 8];
        bf16x8 bb = zero8();
        if (ln < 3) bb = *(const bf16x8*)&W4c[ln * 64 + b * 8];
        accP = __builtin_amdgcn_mfma_f32_32x32x16_bf16(a, bb, accP, 0, 0, 0);
    }
    #pragma unroll
    for (int g = 0; g < 4; g++) {                        // P B-frag [b=i'>>3][n=c][jj]
        bf16x4 p;
        #pragma unroll
        for (int r2 = 0; r2 < 4; r2++) p[r2] = (__bf16)accP[4 * g + r2];
        *(bf16x4*)&ra[g * 264 + ln * 8 + 4 * half] = p;
    }

    // ---- P7: out = A4b @ P + b4, stored straight from C regs
    f32x16 accO;
    #pragma unroll
    for (int z = 0; z < 16; z++) accO[z] = 0.f;
    #pragma unroll
    for (int ks = 0; ks < 2; ks++) {
        bf16x8 a  = *(const bf16x8*)&A4b[(half + 2 * ks) * 256 + ln * 8];
        bf16x8 bb = *(const bf16x8*)&ra[(half + 2 * ks) * 264 + ln * 8];
        accO = __builtin_amdgcn_mfma_f32_32x32x16_bf16(a, bb, accO, 0, 0, 0);
    }
    if (ln < 3) {
        const float b4v = b4s[ln];
        const long ob = (long)f * NJC;
        #pragma unroll
        for (int r = 0; r < 16; r++) {
            const int row = (r & 3) + 8 * (r >> 2) + 4 * half;
            if (row < J) out[ob + row * 3 + ln] = accO[r] + b4v;
        }
    }
}

// ---------------------------------------------------------------------------
extern "C" void kernel_launch(void* const* d_in, const int* in_sizes, int n_in,
                              void* d_out, int out_size, void* d_ws, size_t ws_size,
                              hipStream_t stream)
{
    const float* x  = (const float*)d_in[0];
    const float* A1 = (const float*)d_in[1];
    const float* W1 = (const float*)d_in[2];
    const float* b1 = (const float*)d_in[3];
    const float* A2 = (const float*)d_in[4];
    const float* W2 = (const float*)d_in[5];
    const float* b2 = (const float*)d_in[6];
    const float* A3 = (const float*)d_in[7];
    const float* W3 = (const float*)d_in[8];
    const float* b3 = (const float*)d_in[9];
    const float* A4 = (const float*)d_in[10];
    const float* W4 = (const float*)d_in[11];
    const float* b4 = (const float*)d_in[12];
    float* out = (float*)d_out;

    const int NT = in_sizes[0] / NJC;                 // 65536
    const int nblocks = (NT + F - 1) / F;             // 8192

    gcn_fused<<<nblocks, NTHREADS, 0, stream>>>(
        x, A1, W1, b1, A2, W2, b2, A3, W3, b3, A4, W4, b4, out, NT);
}

// Round 6
// 158.846 us; speedup vs baseline: 3.9697x; 1.2373x over previous
//
#include <hip/hip_runtime.h>
#include <math.h>

#define J 25
#define NJC 75             // J * CIN
#define F 8                // frames per block = waves per block
#define NTHREADS 512
#define SCRW 2112          // per-wave scratch: 8 blocks x 264 bf16 (4224 B)

// const-image layout (bf16 element offsets within the 16384 B block)
#define O_A1T  0
#define O_APP  1024
#define O_A4B  2048
#define O_W2T  3072
#define O_W3T  5120
#define O_W1T  7168
#define O_W4C  7680
#define O_BPP  7936        // fp32[64] bpp, then fp32[64..67] = b4

using bf16x4 = __attribute__((ext_vector_type(4))) __bf16;
using bf16x8 = __attribute__((ext_vector_type(8))) __bf16;
using f32x4  = __attribute__((ext_vector_type(4))) float;
using f32x16 = __attribute__((ext_vector_type(16))) float;

__device__ inline bf16x8 zero8() {
    bf16x8 z;
    #pragma unroll
    for (int j = 0; j < 8; j++) z[j] = (__bf16)0.f;
    return z;
}

// ---------------------------------------------------------------------------
// Precompute (1 block, 256 thr): softmax(A1..A4), App=A3s@A2s, bpp=W3^T b2+b3,
// then emit the COMPLETE bf16 frag-layout constant image to ws. The fused
// kernel copies it verbatim into LDS — zero per-block conversion VALU.
// ---------------------------------------------------------------------------
__global__ void gcn_precompute(
    const float* __restrict__ A1, const float* __restrict__ W1, const float* __restrict__ b1,
    const float* __restrict__ A2, const float* __restrict__ W2, const float* __restrict__ b2,
    const float* __restrict__ A3, const float* __restrict__ W3, const float* __restrict__ b3,
    const float* __restrict__ A4, const float* __restrict__ W4, const float* __restrict__ b4,
    __bf16* __restrict__ cw)
{
    __shared__ float T[3125];      // T0..T3 softmax(A1..A4), T4 = App
    float* T0 = T;        float* T1 = T + 625;  float* T2 = T + 1250;
    float* T3 = T + 1875; float* T4 = T + 2500;
    const int t = threadIdx.x;

    if (t < 100) {
        const int m = t / J, i = t % J;
        const float* Asrc = (m == 0) ? A1 : (m == 1) ? A2 : (m == 2) ? A3 : A4;
        float row[J];
        float mx = -1e30f;
        #pragma unroll
        for (int j = 0; j < J; j++) { row[j] = Asrc[i * J + j]; mx = fmaxf(mx, row[j]); }
        float s = 0.f;
        #pragma unroll
        for (int j = 0; j < J; j++) { row[j] = __expf(row[j] - mx); s += row[j]; }
        const float inv = 1.f / s;
        float* dst = T + m * 625 + i * J;
        #pragma unroll
        for (int j = 0; j < J; j++) dst[j] = row[j] * inv;
    }
    __syncthreads();

    for (int idx = t; idx < 625; idx += 256) {        // App = A3s @ A2s
        const int i = idx / J, jj = idx % J;
        float s = 0.f;
        #pragma unroll
        for (int k = 0; k < J; k++) s += T2[i * J + k] * T1[k * J + jj];
        T4[idx] = s;
    }
    __syncthreads();

    // ---- emit frag-layout tables (mappings R4-verified) ----
    for (int i = t; i < 1024; i += 256) {
        const int b = i >> 8, n = (i >> 3) & 31, jj = i & 7, j = 8 * b + jj;
        const bool ok = (j < J) && (n < J);
        cw[O_A1T + i] = (__bf16)(ok ? T0[n * J + j] : 0.f);   // B-frag [k=j][n=i]
        cw[O_APP + i] = (__bf16)(ok ? T4[n * J + j] : 0.f);   // A-frag [m=i'][k=j]
        cw[O_A4B + i] = (__bf16)(ok ? T3[n * J + j] : 0.f);   // A-frag [m=i''][k=j]
    }
    for (int i = t; i < 2048; i += 256) {
        const int b = i >> 8, m = (i >> 3) & 31, jj = i & 7;
        cw[O_W2T + i] = (__bf16)W2[(8 * b + jj) * 32 + m];             // [m=l][k=d]
        const int tt = i >> 10, r = i & 1023;
        const int b3i = r >> 8, m3 = (r >> 3) & 31, j3 = r & 7;
        cw[O_W3T + i] = (__bf16)W3[(8 * b3i + j3) * 64 + tt * 32 + m3]; // [m=d][k=l]
    }
    for (int i = t; i < 512; i += 256) {
        const int tt = i >> 8, m = (i >> 3) & 31, c = i & 7, d = tt * 32 + m;
        float v = 0.f;
        if (c < 3) v = W1[c * 64 + d];
        else if (c == 3) v = b1[d];
        cw[O_W1T + i] = (__bf16)v;
    }
    if (t < 256)
        cw[O_W4C + t] = (t < 192) ? (__bf16)W4[(t & 63) * 3 + (t >> 6)] : (__bf16)0.f;

    float* fw = (float*)(cw + O_BPP);
    if (t < 64) {                                      // bpp = W3^T b2 + b3
        float s = b3[t];
        #pragma unroll
        for (int l = 0; l < 32; l++) s += W3[l * 64 + t] * b2[l];
        fw[t] = s;
    }
    if (t >= 64 && t < 68) fw[t] = (t < 67) ? b4[t - 64] : 0.f;
}

// ---------------------------------------------------------------------------
// Fused kernel. One frame per WAVE; single 4224 B scratch region per wave
// (8 blocks x 264 bf16 — R5's 2112-element/wave under-allocation FIXED).
// All overlapping scratch writes are data-dependent on the reads they replace,
// and per-wave LDS ops are in-order (R3/R4-proven) -> zero pipeline barriers.
//
// Frag addressing (A and B), bf16: addr = blk*264 + row*8 + (k&7), blk = k>>3
// (scratch; const tables use stride 256).
//
// mfma_f32_32x32x16_bf16 (verified): A[m][k]: m=lane&31, k=8*(lane>>5)+j+16ks
//   B[k][n]: n=lane&31, same k.  C/D: col=lane&31, row=(reg&3)+8*(reg>>2)+4*(lane>>5)
//
// Scratch block schedule (8 blocks of 264 bf16):
//   xT fp32 (block 0, bytes 0-383) -> P2 H (blks 0-7) -> P3 U (blks 0-3)
//   -> P4 V^T (blks 4-7) -> P5 HD (blks 0-7) -> P6 P (blks 0-3)
// ---------------------------------------------------------------------------
__global__ __launch_bounds__(NTHREADS, 6) void gcn_fused(
    const float* __restrict__ x,
    const __bf16* __restrict__ cw,
    float* __restrict__ out, const int NT)
{
    __shared__ __align__(16) __bf16 C0[8192];        // 16384 B const image
    __shared__ __align__(16) __bf16 SCR[F * SCRW];   // 8 x 4224 B

    const int t = threadIdx.x;

    // ---- const image: verbatim copy ws -> LDS (2 x uint4 per thread)
    {
        const uint4* src = (const uint4*)cw;
        uint4* dst = (uint4*)C0;
        dst[t] = src[t];
        dst[t + NTHREADS] = src[t + NTHREADS];
    }
    __syncthreads();

    const __bf16* A1T  = C0 + O_A1T;
    const __bf16* Appb = C0 + O_APP;
    const __bf16* A4b  = C0 + O_A4B;
    const __bf16* W2T  = C0 + O_W2T;
    const __bf16* W3T  = C0 + O_W3T;
    const __bf16* W1T  = C0 + O_W1T;
    const __bf16* W4c  = C0 + O_W4C;
    const float*  bpps = (const float*)(C0 + O_BPP);
    const float*  b4s  = bpps + 64;

    const int w = t >> 6, lane = t & 63, ln = lane & 31, half = lane >> 5;
    const int f = blockIdx.x * F + w;
    if (f >= NT) return;

    __bf16* sc = &SCR[w * SCRW];

    // ---- x staging: transposed xT[c][j] (stride 32 floats), zero-padded
    float* xT = (float*)sc;
    for (int i = lane; i < 96; i += 64) xT[i] = 0.f;
    for (int i = lane; i < NJC; i += 64) {
        const float v = x[(long)f * NJC + i];
        xT[(i % 3) * 32 + (i / 3)] = v;
    }

    // ---- P1: Y^T = X^T_aug @ A1T  (M=c rows 0..3, N=i, K=j pad32)
    bf16x8 xa[2];
    #pragma unroll
    for (int ks = 0; ks < 2; ks++) {
        f32x4 v0, v1;
        #pragma unroll
        for (int z = 0; z < 4; z++) { v0[z] = 0.f; v1[z] = 0.f; }
        if (ln < 3) {
            v0 = *(const f32x4*)&xT[ln * 32 + ks * 16 + half * 8];
            v1 = *(const f32x4*)&xT[ln * 32 + ks * 16 + half * 8 + 4];
        }
        #pragma unroll
        for (int jj = 0; jj < 4; jj++) {
            xa[ks][jj]     = (ln == 3) ? (__bf16)1.f : (__bf16)v0[jj];
            xa[ks][4 + jj] = (ln == 3) ? (__bf16)1.f : (__bf16)v1[jj];
        }
    }
    f32x16 accY;
    #pragma unroll
    for (int z = 0; z < 16; z++) accY[z] = 0.f;
    #pragma unroll
    for (int ks = 0; ks < 2; ks++) {
        bf16x8 bb = *(const bf16x8*)&A1T[(half + 2 * ks) * 256 + ln * 8];
        accY = __builtin_amdgcn_mfma_f32_32x32x16_bf16(xa[ks], bb, accY, 0, 0, 0);
    }

    // ---- P2: H^T = relu(W1T_aug @ Y^T) — Y^T consumed in-register
    bf16x8 yb;
    #pragma unroll
    for (int jj = 0; jj < 8; jj++)
        yb[jj] = (half == 0 && jj < 4) ? (__bf16)accY[jj] : (__bf16)0.f;
    #pragma unroll
    for (int tt = 0; tt < 2; tt++) {
        bf16x8 a = zero8();
        if (half == 0) a = *(const bf16x8*)&W1T[tt * 256 + ln * 8];
        f32x16 acc;
        #pragma unroll
        for (int z = 0; z < 16; z++) acc[z] = 0.f;
        acc = __builtin_amdgcn_mfma_f32_32x32x16_bf16(a, yb, acc, 0, 0, 0);
        #pragma unroll
        for (int g = 0; g < 4; g++) {                    // d = tt*32+8g+4h+r2
            bf16x4 p;
            #pragma unroll
            for (int r2 = 0; r2 < 4; r2++) p[r2] = (__bf16)fmaxf(acc[4 * g + r2], 0.f);
            *(bf16x4*)&sc[(tt * 4 + g) * 264 + ln * 8 + 4 * half] = p;
        }
    }

    // ---- P3: U^T = W2T @ H^T  (M=l, N=i, K=64)
    f32x16 accU;
    #pragma unroll
    for (int z = 0; z < 16; z++) accU[z] = 0.f;
    #pragma unroll
    for (int ks = 0; ks < 4; ks++) {
        const int b = half + 2 * ks;
        bf16x8 a  = *(const bf16x8*)&W2T[b * 256 + ln * 8];
        bf16x8 bb = *(const bf16x8*)&sc[b * 264 + ln * 8];
        accU = __builtin_amdgcn_mfma_f32_32x32x16_bf16(a, bb, accU, 0, 0, 0);
    }
    #pragma unroll
    for (int r = 0; r < 16; r++) {                       // U B-frag [b=j>>3][n=l][jj]
        const int row = (r & 3) + 8 * (r >> 2) + 4 * half;   // l
        sc[(ln >> 3) * 264 + row * 8 + (ln & 7)] = (__bf16)accU[r];  // j = ln
    }

    // ---- P4: V = Appb @ U  (M=i', N=l, K=j pad32)
    f32x16 accV;
    #pragma unroll
    for (int z = 0; z < 16; z++) accV[z] = 0.f;
    #pragma unroll
    for (int ks = 0; ks < 2; ks++) {
        bf16x8 a  = *(const bf16x8*)&Appb[(half + 2 * ks) * 256 + ln * 8];
        bf16x8 bb = *(const bf16x8*)&sc[(half + 2 * ks) * 264 + ln * 8];
        accV = __builtin_amdgcn_mfma_f32_32x32x16_bf16(a, bb, accV, 0, 0, 0);
    }
    #pragma unroll
    for (int r = 0; r < 16; r++) {                       // V^T B-frag, blks 4-7
        const int row = (r & 3) + 8 * (r >> 2) + 4 * half;   // i'
        sc[(4 + (ln >> 3)) * 264 + row * 8 + (ln & 7)] = (__bf16)accV[r];  // l = ln
    }

    // ---- P5: HD^T = relu(W3T @ V^T + bpp)  (M=d 2 tiles, N=i', K=32)
    bf16x8 vb[2];                                        // hoisted B-frags
    #pragma unroll
    for (int ks = 0; ks < 2; ks++)
        vb[ks] = *(const bf16x8*)&sc[(4 + half + 2 * ks) * 264 + ln * 8];
    #pragma unroll
    for (int tt = 0; tt < 2; tt++) {
        f32x16 acc;
        #pragma unroll
        for (int z = 0; z < 16; z++) acc[z] = 0.f;
        #pragma unroll
        for (int ks = 0; ks < 2; ks++) {
            bf16x8 a = *(const bf16x8*)&W3T[tt * 1024 + (half + 2 * ks) * 256 + ln * 8];
            acc = __builtin_amdgcn_mfma_f32_32x32x16_bf16(a, vb[ks], acc, 0, 0, 0);
        }
        #pragma unroll
        for (int g = 0; g < 4; g++) {
            f32x4 bias = *(const f32x4*)&bpps[tt * 32 + 8 * g + 4 * half];
            bf16x4 p;
            #pragma unroll
            for (int r2 = 0; r2 < 4; r2++)
                p[r2] = (__bf16)fmaxf(acc[4 * g + r2] + bias[r2], 0.f);
            *(bf16x4*)&sc[(tt * 4 + g) * 264 + ln * 8 + 4 * half] = p;   // HD A-frag
        }
    }

    // ---- P6: P = HD @ W4c  (M=i', N=c, K=64)
    f32x16 accP;
    #pragma unroll
    for (int z = 0; z < 16; z++) accP[z] = 0.f;
    #pragma unroll
    for (int ks = 0; ks < 4; ks++) {
        const int b = half + 2 * ks;
        bf16x8 a = *(const bf16x8*)&sc[b * 264 + ln * 8];
        bf16x8 bb = zero8();
        if (ln < 3) bb = *(const bf16x8*)&W4c[ln * 64 + b * 8];
        accP = __builtin_amdgcn_mfma_f32_32x32x16_bf16(a, bb, accP, 0, 0, 0);
    }
    #pragma unroll
    for (int g = 0; g < 4; g++) {                        // P B-frag, blks 0-3
        bf16x4 p;
        #pragma unroll
        for (int r2 = 0; r2 < 4; r2++) p[r2] = (__bf16)accP[4 * g + r2];
        *(bf16x4*)&sc[g * 264 + ln * 8 + 4 * half] = p;
    }

    // ---- P7: out = A4b @ P + b4, stored straight from C regs
    f32x16 accO;
    #pragma unroll
    for (int z = 0; z < 16; z++) accO[z] = 0.f;
    #pragma unroll
    for (int ks = 0; ks < 2; ks++) {
        bf16x8 a  = *(const bf16x8*)&A4b[(half + 2 * ks) * 256 + ln * 8];
        bf16x8 bb = *(const bf16x8*)&sc[(half + 2 * ks) * 264 + ln * 8];
        accO = __builtin_amdgcn_mfma_f32_32x32x16_bf16(a, bb, accO, 0, 0, 0);
    }
    if (ln < 3) {
        const float b4v = b4s[ln];
        const long ob = (long)f * NJC;
        #pragma unroll
        for (int r = 0; r < 16; r++) {
            const int row = (r & 3) + 8 * (r >> 2) + 4 * half;
            if (row < J) out[ob + row * 3 + ln] = accO[r] + b4v;
        }
    }
}

// ---------------------------------------------------------------------------
extern "C" void kernel_launch(void* const* d_in, const int* in_sizes, int n_in,
                              void* d_out, int out_size, void* d_ws, size_t ws_size,
                              hipStream_t stream)
{
    const float* x  = (const float*)d_in[0];
    const float* A1 = (const float*)d_in[1];
    const float* W1 = (const float*)d_in[2];
    const float* b1 = (const float*)d_in[3];
    const float* A2 = (const float*)d_in[4];
    const float* W2 = (const float*)d_in[5];
    const float* b2 = (const float*)d_in[6];
    const float* A3 = (const float*)d_in[7];
    const float* W3 = (const float*)d_in[8];
    const float* b3 = (const float*)d_in[9];
    const float* A4 = (const float*)d_in[10];
    const float* W4 = (const float*)d_in[11];
    const float* b4 = (const float*)d_in[12];
    float* out = (float*)d_out;
    __bf16* cw = (__bf16*)d_ws;

    const int NT = in_sizes[0] / NJC;                 // 65536
    const int nblocks = (NT + F - 1) / F;             // 8192

    gcn_precompute<<<1, 256, 0, stream>>>(
        A1, W1, b1, A2, W2, b2, A3, W3, b3, A4, W4, b4, cw);
    gcn_fused<<<nblocks, NTHREADS, 0, stream>>>(x, cw, out, NT);
}

// Round 7
// 158.378 us; speedup vs baseline: 3.9814x; 1.0030x over previous
//
#include <hip/hip_runtime.h>
#include <math.h>

#define J 25
#define NJC 75             // J * CIN
#define F 8                // frames per block = waves per block
#define NTHREADS 512
#define SCRW 2112          // per-wave scratch: 8 blocks x 264 bf16 (4224 B)

// const-image layout (bf16 element offsets); image = 8704 el = 17408 B
#define O_A1T  0
#define O_APP  1024
#define O_A4B  2048
#define O_W2T  3072
#define O_W3T  5120
#define O_W1T  7168        // padded: [tt][half][m][c] = 2*2*32*8, half1 = zeros
#define O_W4C  8192
#define O_BPP  8448        // fp32[64] bpp, then fp32[64..67] = b4
#define C0_EL  8704
#define C0_U4  1088        // 17408 B / 16

using bf16x4 = __attribute__((ext_vector_type(4))) __bf16;
using bf16x8 = __attribute__((ext_vector_type(8))) __bf16;
using f32x4  = __attribute__((ext_vector_type(4))) float;
using f32x16 = __attribute__((ext_vector_type(16))) float;

__device__ inline bf16x8 zero8() {
    bf16x8 z;
    #pragma unroll
    for (int j = 0; j < 8; j++) z[j] = (__bf16)0.f;
    return z;
}

// ---------------------------------------------------------------------------
// Precompute (1 block, 256 thr): softmax(A1..A4), App=A3s@A2s, bpp=W3^T b2+b3,
// then emit the COMPLETE bf16 frag-layout constant image to ws.
// ---------------------------------------------------------------------------
__global__ void gcn_precompute(
    const float* __restrict__ A1, const float* __restrict__ W1, const float* __restrict__ b1,
    const float* __restrict__ A2, const float* __restrict__ W2, const float* __restrict__ b2,
    const float* __restrict__ A3, const float* __restrict__ W3, const float* __restrict__ b3,
    const float* __restrict__ A4, const float* __restrict__ W4, const float* __restrict__ b4,
    __bf16* __restrict__ cw)
{
    __shared__ float T[3125];      // T0..T3 softmax(A1..A4), T4 = App
    float* T0 = T;        float* T1 = T + 625;  float* T2 = T + 1250;
    float* T3 = T + 1875; float* T4 = T + 2500;
    const int t = threadIdx.x;

    if (t < 100) {
        const int m = t / J, i = t % J;
        const float* Asrc = (m == 0) ? A1 : (m == 1) ? A2 : (m == 2) ? A3 : A4;
        float row[J];
        float mx = -1e30f;
        #pragma unroll
        for (int j = 0; j < J; j++) { row[j] = Asrc[i * J + j]; mx = fmaxf(mx, row[j]); }
        float s = 0.f;
        #pragma unroll
        for (int j = 0; j < J; j++) { row[j] = __expf(row[j] - mx); s += row[j]; }
        const float inv = 1.f / s;
        float* dst = T + m * 625 + i * J;
        #pragma unroll
        for (int j = 0; j < J; j++) dst[j] = row[j] * inv;
    }
    __syncthreads();

    for (int idx = t; idx < 625; idx += 256) {        // App = A3s @ A2s
        const int i = idx / J, jj = idx % J;
        float s = 0.f;
        #pragma unroll
        for (int k = 0; k < J; k++) s += T2[i * J + k] * T1[k * J + jj];
        T4[idx] = s;
    }
    __syncthreads();

    // ---- emit frag-layout tables (mappings R4/R6-verified) ----
    for (int i = t; i < 1024; i += 256) {
        const int b = i >> 8, n = (i >> 3) & 31, jj = i & 7, j = 8 * b + jj;
        const bool ok = (j < J) && (n < J);
        cw[O_A1T + i] = (__bf16)(ok ? T0[n * J + j] : 0.f);   // B-frag [k=j][n=i]
        cw[O_APP + i] = (__bf16)(ok ? T4[n * J + j] : 0.f);   // A-frag [m=i'][k=j]
        cw[O_A4B + i] = (__bf16)(ok ? T3[n * J + j] : 0.f);   // A-frag [m=i''][k=j]
    }
    for (int i = t; i < 2048; i += 256) {
        const int b = i >> 8, m = (i >> 3) & 31, jj = i & 7;
        cw[O_W2T + i] = (__bf16)W2[(8 * b + jj) * 32 + m];             // [m=l][k=d]
        const int tt = i >> 10, r = i & 1023;
        const int b3i = r >> 8, m3 = (r >> 3) & 31, j3 = r & 7;
        cw[O_W3T + i] = (__bf16)W3[(8 * b3i + j3) * 64 + tt * 32 + m3]; // [m=d][k=l]
    }
    for (int i = t; i < 1024; i += 256) {             // W1T padded, half1 = 0
        const int tt = i >> 9, r = i & 511, hf = r >> 8, q = r & 255;
        const int m = q >> 3, c = q & 7, d = tt * 32 + m;
        float v = 0.f;
        if (hf == 0) {
            if (c < 3) v = W1[c * 64 + d];
            else if (c == 3) v = b1[d];
        }
        cw[O_W1T + i] = (__bf16)v;
    }
    if (t < 256)
        cw[O_W4C + t] = (t < 192) ? (__bf16)W4[(t & 63) * 3 + (t >> 6)] : (__bf16)0.f;

    float* fw = (float*)(cw + O_BPP);
    if (t < 64) {                                      // bpp = W3^T b2 + b3
        float s = b3[t];
        #pragma unroll
        for (int l = 0; l < 32; l++) s += W3[l * 64 + t] * b2[l];
        fw[t] = s;
    }
    if (t >= 64 && t < 68) fw[t] = (t < 67) ? b4[t - 64] : 0.f;
}

// ---------------------------------------------------------------------------
// Fused kernel. One frame per WAVE; 4224 B scratch/wave (8 blocks x 264 bf16).
// Per-wave LDS ops are in-order -> zero pipeline barriers (R3/R4/R6-proven).
//
// Frag addressing (A and B), bf16: addr = blk*264 + row*8 + (k&7), blk = k>>3
// (scratch; const tables use stride 256).
//
// mfma_f32_32x32x16_bf16 (verified): A[m][k]: m=lane&31, k=8*(lane>>5)+j+16ks
//   B[k][n]: n=lane&31, same k.  C/D: col=lane&31, row=(reg&3)+8*(reg>>2)+4*(lane>>5)
//
// Scratch schedule: X A-frag bf16 (blks 0-3, rows 0-3) -> P2 H (blks 0-7)
//   -> P3 U (blks 0-3) -> P4 V^T (blks 4-7) -> P5 HD (blks 0-7) -> P6 P (blks 0-3)
// ---------------------------------------------------------------------------
__global__ __launch_bounds__(NTHREADS, 6) void gcn_fused(
    const float* __restrict__ x,
    const __bf16* __restrict__ cw,
    float* __restrict__ out, const int NT)
{
    __shared__ __align__(16) __bf16 C0[C0_EL];       // 17408 B const image
    __shared__ __align__(16) __bf16 SCR[F * SCRW];   // 8 x 4224 B

    const int t = threadIdx.x;

    // ---- const image: verbatim copy ws -> LDS
    {
        const uint4* src = (const uint4*)cw;
        uint4* dst = (uint4*)C0;
        for (int i = t; i < C0_U4; i += NTHREADS) dst[i] = src[i];
    }
    __syncthreads();

    const __bf16* A1T  = C0 + O_A1T;
    const __bf16* Appb = C0 + O_APP;
    const __bf16* A4b  = C0 + O_A4B;
    const __bf16* W2T  = C0 + O_W2T;
    const __bf16* W3T  = C0 + O_W3T;
    const __bf16* W1TP = C0 + O_W1T;
    const __bf16* W4c  = C0 + O_W4C;
    const float*  bpps = (const float*)(C0 + O_BPP);
    const float*  b4s  = bpps + 64;

    const int w = t >> 6, lane = t & 63, ln = lane & 31, half = lane >> 5;
    const int f = blockIdx.x * F + w;
    if (f >= NT) return;

    __bf16* sc = &SCR[w * SCRW];

    // ---- shared zero accumulator (MFMA allows D != C): 16 movs for the kernel
    f32x16 Z;
    #pragma unroll
    for (int z = 0; z < 16; z++) Z[z] = 0.f;

    // ---- X staged directly as bf16 A-frag: blks 0-3, rows 0-3 (m=c + ones)
    {
        // zero-fill rows 0-3 of blocks 0-3 (128 bf16 via 64 b32 writes)
        const int blk = lane >> 4, row = (lane >> 2) & 3, q = (lane & 3) * 2;
        *(unsigned int*)&sc[blk * 264 + row * 8 + q] = 0u;
        // ones row m=3, k=0..24 (bias slot; k>=25 stays 0)
        if (lane < J) sc[(lane >> 3) * 264 + 24 + (lane & 7)] = (__bf16)1.f;
        // scatter x: element i -> m=c=i%3, k=j=i/3
        for (int i = lane; i < NJC; i += 64) {
            const float v = x[(long)f * NJC + i];
            const int c = i % 3, j = i / 3;
            sc[(j >> 3) * 264 + c * 8 + (j & 7)] = (__bf16)v;
        }
    }

    // ---- P1: Y^T = X_aug^T @ A1T  (M=c rows 0..3, N=i, K=j pad32)
    f32x16 accY;
    {
        bf16x8 a0 = *(const bf16x8*)&sc[(half)*264 + ln * 8];
        bf16x8 b0 = *(const bf16x8*)&A1T[(half)*256 + ln * 8];
        accY = __builtin_amdgcn_mfma_f32_32x32x16_bf16(a0, b0, Z, 0, 0, 0);
        bf16x8 a1 = *(const bf16x8*)&sc[(2 + half) * 264 + ln * 8];
        bf16x8 b1 = *(const bf16x8*)&A1T[(2 + half) * 256 + ln * 8];
        accY = __builtin_amdgcn_mfma_f32_32x32x16_bf16(a1, b1, accY, 0, 0, 0);
    }

    // ---- P2: H^T = relu(W1TP @ Y^T) — Y^T consumed in-register
    bf16x8 yb;
    #pragma unroll
    for (int jj = 0; jj < 8; jj++)
        yb[jj] = (half == 0 && jj < 4) ? (__bf16)accY[jj] : (__bf16)0.f;
    #pragma unroll
    for (int tt = 0; tt < 2; tt++) {
        bf16x8 a = *(const bf16x8*)&W1TP[tt * 512 + half * 256 + ln * 8];
        f32x16 acc = __builtin_amdgcn_mfma_f32_32x32x16_bf16(a, yb, Z, 0, 0, 0);
        #pragma unroll
        for (int g = 0; g < 4; g++) {                    // d = tt*32+8g+4h+r2
            bf16x4 p;
            #pragma unroll
            for (int r2 = 0; r2 < 4; r2++) p[r2] = (__bf16)fmaxf(acc[4 * g + r2], 0.f);
            *(bf16x4*)&sc[(tt * 4 + g) * 264 + ln * 8 + 4 * half] = p;
        }
    }

    // ---- P3: U^T = W2T @ H^T  (M=l, N=i, K=64)
    f32x16 accU;
    {
        bf16x8 a0 = *(const bf16x8*)&W2T[half * 256 + ln * 8];
        bf16x8 b0 = *(const bf16x8*)&sc[half * 264 + ln * 8];
        accU = __builtin_amdgcn_mfma_f32_32x32x16_bf16(a0, b0, Z, 0, 0, 0);
        #pragma unroll
        for (int ks = 1; ks < 4; ks++) {
            const int b = half + 2 * ks;
            bf16x8 a  = *(const bf16x8*)&W2T[b * 256 + ln * 8];
            bf16x8 bb = *(const bf16x8*)&sc[b * 264 + ln * 8];
            accU = __builtin_amdgcn_mfma_f32_32x32x16_bf16(a, bb, accU, 0, 0, 0);
        }
    }
    #pragma unroll
    for (int r = 0; r < 16; r++) {                       // U B-frag [b=j>>3][n=l][jj]
        const int row = (r & 3) + 8 * (r >> 2) + 4 * half;   // l
        sc[(ln >> 3) * 264 + row * 8 + (ln & 7)] = (__bf16)accU[r];  // j = ln
    }

    // ---- P4: V = Appb @ U  (M=i', N=l, K=j pad32)
    f32x16 accV;
    {
        bf16x8 a0 = *(const bf16x8*)&Appb[half * 256 + ln * 8];
        bf16x8 b0 = *(const bf16x8*)&sc[half * 264 + ln * 8];
        accV = __builtin_amdgcn_mfma_f32_32x32x16_bf16(a0, b0, Z, 0, 0, 0);
        bf16x8 a1 = *(const bf16x8*)&Appb[(2 + half) * 256 + ln * 8];
        bf16x8 b1 = *(const bf16x8*)&sc[(2 + half) * 264 + ln * 8];
        accV = __builtin_amdgcn_mfma_f32_32x32x16_bf16(a1, b1, accV, 0, 0, 0);
    }
    #pragma unroll
    for (int r = 0; r < 16; r++) {                       // V^T B-frag, blks 4-7
        const int row = (r & 3) + 8 * (r >> 2) + 4 * half;   // i'
        sc[(4 + (ln >> 3)) * 264 + row * 8 + (ln & 7)] = (__bf16)accV[r];  // l = ln
    }

    // ---- P5: HD^T = relu(W3T @ V^T + bpp)  (M=d 2 tiles, N=i', K=32)
    bf16x8 vb[2];                                        // hoisted B-frags
    #pragma unroll
    for (int ks = 0; ks < 2; ks++)
        vb[ks] = *(const bf16x8*)&sc[(4 + half + 2 * ks) * 264 + ln * 8];
    #pragma unroll
    for (int tt = 0; tt < 2; tt++) {
        bf16x8 a0 = *(const bf16x8*)&W3T[tt * 1024 + half * 256 + ln * 8];
        f32x16 acc = __builtin_amdgcn_mfma_f32_32x32x16_bf16(a0, vb[0], Z, 0, 0, 0);
        bf16x8 a1 = *(const bf16x8*)&W3T[tt * 1024 + (2 + half) * 256 + ln * 8];
        acc = __builtin_amdgcn_mfma_f32_32x32x16_bf16(a1, vb[1], acc, 0, 0, 0);
        #pragma unroll
        for (int g = 0; g < 4; g++) {
            f32x4 bias = *(const f32x4*)&bpps[tt * 32 + 8 * g + 4 * half];
            bf16x4 p;
            #pragma unroll
            for (int r2 = 0; r2 < 4; r2++)
                p[r2] = (__bf16)fmaxf(acc[4 * g + r2] + bias[r2], 0.f);
            *(bf16x4*)&sc[(tt * 4 + g) * 264 + ln * 8 + 4 * half] = p;   // HD A-frag
        }
    }

    // ---- P6: P = HD @ W4c  (M=i', N=c, K=64)
    f32x16 accP;
    {
        bf16x8 a0 = *(const bf16x8*)&sc[half * 264 + ln * 8];
        bf16x8 b0 = zero8();
        if (ln < 3) b0 = *(const bf16x8*)&W4c[ln * 64 + half * 8];
        accP = __builtin_amdgcn_mfma_f32_32x32x16_bf16(a0, b0, Z, 0, 0, 0);
        #pragma unroll
        for (int ks = 1; ks < 4; ks++) {
            const int b = half + 2 * ks;
            bf16x8 a = *(const bf16x8*)&sc[b * 264 + ln * 8];
            bf16x8 bb = zero8();
            if (ln < 3) bb = *(const bf16x8*)&W4c[ln * 64 + b * 8];
            accP = __builtin_amdgcn_mfma_f32_32x32x16_bf16(a, bb, accP, 0, 0, 0);
        }
    }
    #pragma unroll
    for (int g = 0; g < 4; g++) {                        // P B-frag, blks 0-3
        bf16x4 p;
        #pragma unroll
        for (int r2 = 0; r2 < 4; r2++) p[r2] = (__bf16)accP[4 * g + r2];
        *(bf16x4*)&sc[g * 264 + ln * 8 + 4 * half] = p;
    }

    // ---- P7: out = A4b @ P + b4, stored straight from C regs
    f32x16 accO;
    {
        bf16x8 a0 = *(const bf16x8*)&A4b[half * 256 + ln * 8];
        bf16x8 b0 = *(const bf16x8*)&sc[half * 264 + ln * 8];
        accO = __builtin_amdgcn_mfma_f32_32x32x16_bf16(a0, b0, Z, 0, 0, 0);
        bf16x8 a1 = *(const bf16x8*)&A4b[(2 + half) * 256 + ln * 8];
        bf16x8 b1 = *(const bf16x8*)&sc[(2 + half) * 264 + ln * 8];
        accO = __builtin_amdgcn_mfma_f32_32x32x16_bf16(a1, b1, accO, 0, 0, 0);
    }
    if (ln < 3) {
        const float b4v = b4s[ln];
        const long ob = (long)f * NJC;
        #pragma unroll
        for (int r = 0; r < 16; r++) {
            const int row = (r & 3) + 8 * (r >> 2) + 4 * half;
            if (row < J) out[ob + row * 3 + ln] = accO[r] + b4v;
        }
    }
}

// ---------------------------------------------------------------------------
extern "C" void kernel_launch(void* const* d_in, const int* in_sizes, int n_in,
                              void* d_out, int out_size, void* d_ws, size_t ws_size,
                              hipStream_t stream)
{
    const float* x  = (const float*)d_in[0];
    const float* A1 = (const float*)d_in[1];
    const float* W1 = (const float*)d_in[2];
    const float* b1 = (const float*)d_in[3];
    const float* A2 = (const float*)d_in[4];
    const float* W2 = (const float*)d_in[5];
    const float* b2 = (const float*)d_in[6];
    const float* A3 = (const float*)d_in[7];
    const float* W3 = (const float*)d_in[8];
    const float* b3 = (const float*)d_in[9];
    const float* A4 = (const float*)d_in[10];
    const float* W4 = (const float*)d_in[11];
    const float* b4 = (const float*)d_in[12];
    float* out = (float*)d_out;
    __bf16* cw = (__bf16*)d_ws;

    const int NT = in_sizes[0] / NJC;                 // 65536
    const int nblocks = (NT + F - 1) / F;             // 8192

    gcn_precompute<<<1, 256, 0, stream>>>(
        A1, W1, b1, A2, W2, b2, A3, W3, b3, A4, W4, b4, cw);
    gcn_fused<<<nblocks, NTHREADS, 0, stream>>>(x, cw, out, NT);
}

// Round 8
// 153.666 us; speedup vs baseline: 4.1035x; 1.0307x over previous
//
#include <hip/hip_runtime.h>
#include <math.h>

#define J 25
#define NJC 75             // J * CIN
#define NWAVE 4            // waves per block
#define NTHREADS 256
#define NFPW 8             // frames per wave
#define SCRW 2112          // per-wave scratch: 8 blocks x 264 bf16 (4224 B)

// const-image layout (bf16 element offsets in ws)
#define O_A1T  0           // B-frag [k=j][n=i], 1024
#define O_APP  1024        // frag [i'][j], 1024 (serves as A or B^T)
#define O_A4B  2048        // A-frag [m=i''][k=j], 1024
#define O_W2T  3072        // frag [l][d], 2048 (serves as A or B)
#define O_W3T  5120        // A-frag [m=d][k=l], 2 M-tiles, 2048
#define O_W1T  7168        // padded [tt][half][m][c8], half1=0, 1024
#define O_W4C  8192        // [n=c][k=d], 256
#define O_BPPB 8448        // 64 bf16: [(tt*2+half)*16 + g*4 + r2] = bpp[tt*32+8g+4half+r2]
#define O_B4   8512        // 4 floats (8 bf16 slots)

using bf16x4 = __attribute__((ext_vector_type(4))) __bf16;
using bf16x8 = __attribute__((ext_vector_type(8))) __bf16;
using f32x16 = __attribute__((ext_vector_type(16))) float;

__device__ inline bf16x8 zero8() {
    bf16x8 z;
    #pragma unroll
    for (int j = 0; j < 8; j++) z[j] = (__bf16)0.f;
    return z;
}

// ---------------------------------------------------------------------------
// Precompute (1 block, 256 thr): softmax(A1..A4), App=A3s@A2s, bpp=W3^T b2+b3,
// then emit the complete bf16 frag-layout constant image to ws.
// ---------------------------------------------------------------------------
__global__ void gcn_precompute(
    const float* __restrict__ A1, const float* __restrict__ W1, const float* __restrict__ b1,
    const float* __restrict__ A2, const float* __restrict__ W2, const float* __restrict__ b2,
    const float* __restrict__ A3, const float* __restrict__ W3, const float* __restrict__ b3,
    const float* __restrict__ A4, const float* __restrict__ W4, const float* __restrict__ b4,
    __bf16* __restrict__ cw)
{
    __shared__ float T[3125];      // T0..T3 softmax(A1..A4), T4 = App
    __shared__ float bpp[64];
    float* T0 = T;        float* T1 = T + 625;  float* T2 = T + 1250;
    float* T3 = T + 1875; float* T4 = T + 2500;
    const int t = threadIdx.x;

    if (t < 100) {
        const int m = t / J, i = t % J;
        const float* Asrc = (m == 0) ? A1 : (m == 1) ? A2 : (m == 2) ? A3 : A4;
        float row[J];
        float mx = -1e30f;
        #pragma unroll
        for (int j = 0; j < J; j++) { row[j] = Asrc[i * J + j]; mx = fmaxf(mx, row[j]); }
        float s = 0.f;
        #pragma unroll
        for (int j = 0; j < J; j++) { row[j] = __expf(row[j] - mx); s += row[j]; }
        const float inv = 1.f / s;
        float* dst = T + m * 625 + i * J;
        #pragma unroll
        for (int j = 0; j < J; j++) dst[j] = row[j] * inv;
    }
    if (t < 64) {                                      // bpp = W3^T b2 + b3
        float s = b3[t];
        #pragma unroll
        for (int l = 0; l < 32; l++) s += W3[l * 64 + t] * b2[l];
        bpp[t] = s;
    }
    __syncthreads();

    for (int idx = t; idx < 625; idx += 256) {        // App = A3s @ A2s
        const int i = idx / J, jj = idx % J;
        float s = 0.f;
        #pragma unroll
        for (int k = 0; k < J; k++) s += T2[i * J + k] * T1[k * J + jj];
        T4[idx] = s;
    }
    __syncthreads();

    // ---- frag-layout tables (mappings R4/R6/R7-verified) ----
    for (int i = t; i < 1024; i += 256) {
        const int b = i >> 8, n = (i >> 3) & 31, jj = i & 7, j = 8 * b + jj;
        const bool ok = (j < J) && (n < J);
        cw[O_A1T + i] = (__bf16)(ok ? T0[n * J + j] : 0.f);
        cw[O_APP + i] = (__bf16)(ok ? T4[n * J + j] : 0.f);
        cw[O_A4B + i] = (__bf16)(ok ? T3[n * J + j] : 0.f);
    }
    for (int i = t; i < 2048; i += 256) {
        const int b = i >> 8, m = (i >> 3) & 31, jj = i & 7;
        cw[O_W2T + i] = (__bf16)W2[(8 * b + jj) * 32 + m];             // [l][d]
        const int tt = i >> 10, r = i & 1023;
        const int b3i = r >> 8, m3 = (r >> 3) & 31, j3 = r & 7;
        cw[O_W3T + i] = (__bf16)W3[(8 * b3i + j3) * 64 + tt * 32 + m3]; // [m=d][k=l]
    }
    for (int i = t; i < 1024; i += 256) {             // W1T padded, half1 = 0
        const int tt = i >> 9, r = i & 511, hf = r >> 8, q = r & 255;
        const int m = q >> 3, c = q & 7, d = tt * 32 + m;
        float v = 0.f;
        if (hf == 0) {
            if (c < 3) v = W1[c * 64 + d];
            else if (c == 3) v = b1[d];
        }
        cw[O_W1T + i] = (__bf16)v;
    }
    if (t < 256)
        cw[O_W4C + t] = (t < 192) ? (__bf16)W4[(t & 63) * 3 + (t >> 6)] : (__bf16)0.f;

    if (t < 64) {                                      // packed bias table
        const int tt = t >> 5, rem = t & 31, hf = rem >> 4, q = rem & 15;
        const int g = q >> 2, r2 = q & 3;
        cw[O_BPPB + t] = (__bf16)bpp[tt * 32 + 8 * g + 4 * hf + r2];
    }
    float* fb4 = (float*)(cw + O_B4);
    if (t >= 64 && t < 68) fb4[t - 64] = (t < 67) ? b4[t - 64] : 0.f;
}

// ---------------------------------------------------------------------------
// Fused kernel. One wave processes NFPW=8 frames; ALL weight/adjacency frags
// register-resident (loaded once per wave from ws via global dwordx4).
// LDS = per-wave scratch only (8 blocks x 264 bf16). Per-wave DS ops are
// in-order -> zero barriers (R3..R7-proven).
//
// Key fact: A-frag and B-frag LDS addressing are the SAME function
// (lane = m or n, k split as blk=k>>3, slot=k&7), so a stored frag serves as
// either operand; swapping operand order in P3/P4 puts the next stage's K-dim
// in the C-register row dim -> b64-packed transposes everywhere (no b16 scatters).
//
// mfma_f32_32x32x16_bf16 (verified): A[m][k]: m=lane&31, k=8*(lane>>5)+j+16ks
//   B[k][n]: n=lane&31, same k.  C/D: col=lane&31, row=(reg&3)+8*(reg>>2)+4*(lane>>5)
//
// Scratch schedule: X A-frag rows 0-3 (blks 0-3) -> P2 H (blks 0-7)
//   -> P3 U (blks 0-3) -> P4 V^T (blks 4-7) -> P5 HD (blks 0-7) -> P6 P (blks 0-3)
// ---------------------------------------------------------------------------
__global__ __launch_bounds__(NTHREADS, 3) void gcn_fused(
    const float* __restrict__ x,
    const __bf16* __restrict__ cw,
    float* __restrict__ out)
{
    __shared__ __align__(16) __bf16 SCR[NWAVE * SCRW];

    const int t = threadIdx.x;
    const int w = t >> 6, lane = t & 63, ln = lane & 31, half = lane >> 5;
    const int fo = ln * 8;
    __bf16* sc = &SCR[w * SCRW];

    const long fbase = ((long)blockIdx.x * NWAVE + w) * NFPW;

    // ---- first-frame x prefetch (issue before the frag loads)
    long xb = fbase * NJC;
    float xv0 = x[xb + lane];
    float xv1 = (lane < NJC - 64) ? x[xb + 64 + lane] : 0.f;

    // ---- register frag loads (once per wave, from global ws image)
    bf16x8 rA1T[2], rApp[2], rA4b[2], rW1[2], rW2[4], rW3[4], rW4[4], rBpp[4];
    #pragma unroll
    for (int ks = 0; ks < 2; ks++) {
        rA1T[ks] = *(const bf16x8*)&cw[O_A1T + (2 * ks + half) * 256 + fo];
        rApp[ks] = *(const bf16x8*)&cw[O_APP + (2 * ks + half) * 256 + fo];
        rA4b[ks] = *(const bf16x8*)&cw[O_A4B + (2 * ks + half) * 256 + fo];
        rW1[ks]  = *(const bf16x8*)&cw[O_W1T + ks * 512 + half * 256 + fo];
    }
    #pragma unroll
    for (int ks = 0; ks < 4; ks++)
        rW2[ks] = *(const bf16x8*)&cw[O_W2T + (half + 2 * ks) * 256 + fo];
    #pragma unroll
    for (int tt = 0; tt < 2; tt++)
        #pragma unroll
        for (int ks = 0; ks < 2; ks++)
            rW3[tt * 2 + ks] = *(const bf16x8*)&cw[O_W3T + tt * 1024 + (half + 2 * ks) * 256 + fo];
    #pragma unroll
    for (int ks = 0; ks < 4; ks++) {
        rW4[ks] = zero8();
        if (ln < 3) rW4[ks] = *(const bf16x8*)&cw[O_W4C + ln * 64 + (half + 2 * ks) * 8];
    }
    #pragma unroll
    for (int tt = 0; tt < 2; tt++)
        #pragma unroll
        for (int p = 0; p < 2; p++)
            rBpp[tt * 2 + p] = *(const bf16x8*)&cw[O_BPPB + (tt * 2 + half) * 16 + p * 8];
    float b4v = 0.f;
    if (ln < 3) b4v = ((const float*)(cw + O_B4))[ln];

    // ---- shared zero accumulator (MFMA allows D != C)
    f32x16 Z;
    #pragma unroll
    for (int z = 0; z < 16; z++) Z[z] = 0.f;

    for (int fi = 0; fi < NFPW; fi++) {
        const long f = fbase + fi;

        // ---- X staging: A-frag rows 0-2 = channels, row 3 = ones (bias slot)
        // (rows 4-31 hold stale junk -> pollutes only discarded C rows)
        {
            const int i0 = lane, c0 = i0 % 3, j0 = i0 / 3;
            sc[(j0 >> 3) * 264 + c0 * 8 + (j0 & 7)] = (__bf16)xv0;
            if (lane < NJC - 64) {
                const int i1 = 64 + lane, c1 = i1 % 3, j1 = i1 / 3;
                sc[(j1 >> 3) * 264 + c1 * 8 + (j1 & 7)] = (__bf16)xv1;
            }
            // ones row (m=3), all 32 k-slots: 1 for k<25, 0 for pad
            if (half == 0) sc[(ln >> 3) * 264 + 24 + (ln & 7)] = (ln < J) ? (__bf16)1.f : (__bf16)0.f;
            // zero k=25..31 pads on rows 0-2 (blk 3, slots 1..7)
            if (lane < 21) sc[3 * 264 + (lane / 7) * 8 + 1 + (lane % 7)] = (__bf16)0.f;
        }

        // ---- prefetch next frame's x
        float nxv0 = 0.f, nxv1 = 0.f;
        if (fi + 1 < NFPW) {
            const long nxb = (f + 1) * NJC;
            nxv0 = x[nxb + lane];
            if (lane < NJC - 64) nxv1 = x[nxb + 64 + lane];
        }

        // ---- P1: Y^T = X_aug^T @ A1T  (M=c rows 0..3, N=i, K=j pad32)
        f32x16 accY;
        {
            bf16x8 a0 = *(const bf16x8*)&sc[half * 264 + fo];
            accY = __builtin_amdgcn_mfma_f32_32x32x16_bf16(a0, rA1T[0], Z, 0, 0, 0);
            bf16x8 a1 = *(const bf16x8*)&sc[(2 + half) * 264 + fo];
            accY = __builtin_amdgcn_mfma_f32_32x32x16_bf16(a1, rA1T[1], accY, 0, 0, 0);
        }

        // ---- P2: H^T = relu(W1TP @ Y^T) — Y^T consumed in-register
        bf16x8 yb;
        #pragma unroll
        for (int jj = 0; jj < 8; jj++)
            yb[jj] = (half == 0 && jj < 4) ? (__bf16)accY[jj] : (__bf16)0.f;
        #pragma unroll
        for (int tt = 0; tt < 2; tt++) {
            f32x16 acc = __builtin_amdgcn_mfma_f32_32x32x16_bf16(rW1[tt], yb, Z, 0, 0, 0);
            #pragma unroll
            for (int g = 0; g < 4; g++) {                    // d = tt*32+8g+4h+r2
                bf16x4 p;
                #pragma unroll
                for (int r2 = 0; r2 < 4; r2++) p[r2] = (__bf16)fmaxf(acc[4 * g + r2], 0.f);
                *(bf16x4*)&sc[(tt * 4 + g) * 264 + fo + 4 * half] = p;
            }
        }

        // ---- P3: U = H @ W2 (operand-swapped: M=i, N=l, K=d) -> C rows = i = next K
        f32x16 accU;
        {
            bf16x8 a0 = *(const bf16x8*)&sc[half * 264 + fo];
            accU = __builtin_amdgcn_mfma_f32_32x32x16_bf16(a0, rW2[0], Z, 0, 0, 0);
            #pragma unroll
            for (int ks = 1; ks < 4; ks++) {
                bf16x8 a = *(const bf16x8*)&sc[(half + 2 * ks) * 264 + fo];
                accU = __builtin_amdgcn_mfma_f32_32x32x16_bf16(a, rW2[ks], accU, 0, 0, 0);
            }
        }
        #pragma unroll
        for (int g = 0; g < 4; g++) {                        // U frag [k=j][n=l], blks 0-3
            bf16x4 p;
            #pragma unroll
            for (int r2 = 0; r2 < 4; r2++) p[r2] = (__bf16)accU[4 * g + r2];
            *(bf16x4*)&sc[g * 264 + fo + 4 * half] = p;
        }

        // ---- P4: V^T = U^T @ App^T (operand-swapped: M=l, N=i', K=j) -> rows = l
        f32x16 accV;
        {
            bf16x8 a0 = *(const bf16x8*)&sc[half * 264 + fo];
            accV = __builtin_amdgcn_mfma_f32_32x32x16_bf16(a0, rApp[0], Z, 0, 0, 0);
            bf16x8 a1 = *(const bf16x8*)&sc[(2 + half) * 264 + fo];
            accV = __builtin_amdgcn_mfma_f32_32x32x16_bf16(a1, rApp[1], accV, 0, 0, 0);
        }
        #pragma unroll
        for (int g = 0; g < 4; g++) {                        // V^T frag [k=l][n=i'], blks 4-7
            bf16x4 p;
            #pragma unroll
            for (int r2 = 0; r2 < 4; r2++) p[r2] = (__bf16)accV[4 * g + r2];
            *(bf16x4*)&sc[(4 + g) * 264 + fo + 4 * half] = p;
        }

        // ---- P5: HD^T = relu(W3T @ V^T + bpp)  (M=d 2 tiles, N=i', K=32)
        bf16x8 vb0 = *(const bf16x8*)&sc[(4 + half) * 264 + fo];
        bf16x8 vb1 = *(const bf16x8*)&sc[(6 + half) * 264 + fo];
        #pragma unroll
        for (int tt = 0; tt < 2; tt++) {
            f32x16 acc = __builtin_amdgcn_mfma_f32_32x32x16_bf16(rW3[tt * 2 + 0], vb0, Z, 0, 0, 0);
            acc = __builtin_amdgcn_mfma_f32_32x32x16_bf16(rW3[tt * 2 + 1], vb1, acc, 0, 0, 0);
            #pragma unroll
            for (int g = 0; g < 4; g++) {
                bf16x4 p;
                #pragma unroll
                for (int r2 = 0; r2 < 4; r2++) {
                    const int q = g * 4 + r2;
                    const float bias = (float)rBpp[tt * 2 + (q >> 3)][q & 7];
                    p[r2] = (__bf16)fmaxf(acc[4 * g + r2] + bias, 0.f);
                }
                *(bf16x4*)&sc[(tt * 4 + g) * 264 + fo + 4 * half] = p;   // HD frag, blks 0-7
            }
        }

        // ---- P6: P = HD @ W4c  (M=i', N=c, K=64) -> rows = i' = next K
        f32x16 accP;
        {
            bf16x8 a0 = *(const bf16x8*)&sc[half * 264 + fo];
            accP = __builtin_amdgcn_mfma_f32_32x32x16_bf16(a0, rW4[0], Z, 0, 0, 0);
            #pragma unroll
            for (int ks = 1; ks < 4; ks++) {
                bf16x8 a = *(const bf16x8*)&sc[(half + 2 * ks) * 264 + fo];
                accP = __builtin_amdgcn_mfma_f32_32x32x16_bf16(a, rW4[ks], accP, 0, 0, 0);
            }
        }
        #pragma unroll
        for (int g = 0; g < 4; g++) {                        // P frag [k=i'][n=c], blks 0-3
            bf16x4 p;
            #pragma unroll
            for (int r2 = 0; r2 < 4; r2++) p[r2] = (__bf16)accP[4 * g + r2];
            *(bf16x4*)&sc[g * 264 + fo + 4 * half] = p;
        }

        // ---- P7: out = A4b @ P + b4, stored straight from C regs
        f32x16 accO;
        {
            bf16x8 b0 = *(const bf16x8*)&sc[half * 264 + fo];
            accO = __builtin_amdgcn_mfma_f32_32x32x16_bf16(rA4b[0], b0, Z, 0, 0, 0);
            bf16x8 b1 = *(const bf16x8*)&sc[(2 + half) * 264 + fo];
            accO = __builtin_amdgcn_mfma_f32_32x32x16_bf16(rA4b[1], b1, accO, 0, 0, 0);
        }
        if (ln < 3) {
            const long ob = f * NJC;
            #pragma unroll
            for (int r = 0; r < 16; r++) {
                const int row = (r & 3) + 8 * (r >> 2) + 4 * half;
                if (row < J) out[ob + row * 3 + ln] = accO[r] + b4v;
            }
        }

        xv0 = nxv0; xv1 = nxv1;
    }
}

// ---------------------------------------------------------------------------
extern "C" void kernel_launch(void* const* d_in, const int* in_sizes, int n_in,
                              void* d_out, int out_size, void* d_ws, size_t ws_size,
                              hipStream_t stream)
{
    const float* x  = (const float*)d_in[0];
    const float* A1 = (const float*)d_in[1];
    const float* W1 = (const float*)d_in[2];
    const float* b1 = (const float*)d_in[3];
    const float* A2 = (const float*)d_in[4];
    const float* W2 = (const float*)d_in[5];
    const float* b2 = (const float*)d_in[6];
    const float* A3 = (const float*)d_in[7];
    const float* W3 = (const float*)d_in[8];
    const float* b3 = (const float*)d_in[9];
    const float* A4 = (const float*)d_in[10];
    const float* W4 = (const float*)d_in[11];
    const float* b4 = (const float*)d_in[12];
    float* out = (float*)d_out;
    __bf16* cw = (__bf16*)d_ws;

    const int NT = in_sizes[0] / NJC;                 // 65536
    const int nblocks = NT / (NWAVE * NFPW);          // 2048

    gcn_precompute<<<1, 256, 0, stream>>>(
        A1, W1, b1, A2, W2, b2, A3, W3, b3, A4, W4, b4, cw);
    gcn_fused<<<nblocks, NTHREADS, 0, stream>>>(x, cw, out);
}